// Round 4
// baseline (302.661 us; speedup 1.0000x reference)
//
#include <hip/hip_runtime.h>
#include <hip/hip_bf16.h>
#include <math.h>

#define D     256
#define D2    512
#define HH    8192
#define NAG   64
#define NROWS 2048
#define KSPL  8     // recall K-split
#define QSPL  32    // query/exp h-split

typedef short  s16x8 __attribute__((ext_vector_type(8)));
typedef __bf16 b16x8 __attribute__((ext_vector_type(8)));
typedef float  f32x4 __attribute__((ext_vector_type(4)));

template <typename T>
__device__ __forceinline__ auto mfma_try(T a, T b, f32x4 c, int)
    -> decltype(__builtin_amdgcn_mfma_f32_16x16x32_bf16(a, b, c, 0, 0, 0))
{ return __builtin_amdgcn_mfma_f32_16x16x32_bf16(a, b, c, 0, 0, 0); }

template <typename T>
__device__ __forceinline__ f32x4 mfma_try(T a, T b, f32x4 c, long)
{
    return __builtin_amdgcn_mfma_f32_16x16x32_bf16(
        __builtin_bit_cast(b16x8, a), __builtin_bit_cast(b16x8, b), c, 0, 0, 0);
}

__device__ __forceinline__ f32x4 MFMA(s16x8 a, s16x8 b, f32x4 c)
{ return mfma_try(a, b, c, 0); }

__device__ __forceinline__ float gelu_f(float x) {
    return 0.5f * x * (1.0f + erff(x * 0.70710678118654752440f));
}
__device__ __forceinline__ float sigmoid_f(float x) {
    return 1.0f / (1.0f + expf(-x));
}
__device__ __forceinline__ short f2bf(float x) {
    __hip_bfloat16 h(x);
    return __builtin_bit_cast(short, h);
}
__device__ __forceinline__ float bf2f(short s) {
    unsigned u = ((unsigned)(unsigned short)s) << 16;
    return __builtin_bit_cast(float, u);
}

// ------------------------------------------------ transpose f32 -> bf16
__device__ __forceinline__ void transpose_body(
    const float* __restrict__ src, short* __restrict__ dst, int R, int C, int lb)
{
    __shared__ float tl[64][65];
    const int t = threadIdx.x;
    const int Ctiles = C >> 6;
    const int bc = lb % Ctiles, br = lb / Ctiles;
    const int r0 = br * 64, c0 = bc * 64;
    for (int p = 0; p < 16; ++p) {
        int e = p * 256 + t; int i = e >> 6, j = e & 63;
        tl[i][j] = src[(size_t)(r0 + i) * C + c0 + j];
    }
    __syncthreads();
    for (int p = 0; p < 16; ++p) {
        int e = p * 256 + t; int jj = e >> 6, ii = e & 63;
        dst[(size_t)(c0 + jj) * R + r0 + ii] = f2bf(tl[ii][jj]);
    }
}

__global__ __launch_bounds__(256) void k_transpose_bf(
    const float* __restrict__ src, short* __restrict__ dst, int R, int C)
{
    transpose_body(src, dst, R, C, blockIdx.x);
}

__global__ __launch_bounds__(256) void k_transpose_small(
    const float* __restrict__ Wp,  const float* __restrict__ Wd1,
    const float* __restrict__ Wd2, const float* __restrict__ Wg,
    const float* __restrict__ Wa,
    short* __restrict__ WpT,  short* __restrict__ Wd1T,
    short* __restrict__ Wd2T, short* __restrict__ WgT,
    short* __restrict__ WaT)
{
    const int b = blockIdx.x;
    const float* src; short* dst; int R, C, b0;
    if      (b < 32)  { src = Wp;  dst = WpT;  R = 512; C = 256; b0 = 0;   }
    else if (b < 64)  { src = Wd1; dst = Wd1T; R = 512; C = 256; b0 = 32;  }
    else if (b < 80)  { src = Wd2; dst = Wd2T; R = 256; C = 256; b0 = 64;  }
    else if (b < 112) { src = Wg;  dst = WgT;  R = 512; C = 256; b0 = 80;  }
    else              { src = Wa;  dst = WaT;  R = 256; C = 256; b0 = 112; }
    transpose_body(src, dst, R, C, b - b0);
}

// ------------------------------------------------ prep: ebf = bf16(ep+cr)
__global__ __launch_bounds__(256) void k_prep_e(
    const float* __restrict__ ep, const float* __restrict__ cr, short* __restrict__ ebf)
{
    const size_t i0 = ((size_t)blockIdx.x * 256 + threadIdx.x) * 8;
    const size_t stride = (size_t)gridDim.x * 256 * 8;
    for (size_t i = i0; i < (size_t)NROWS * HH; i += stride) {
        float4 e0 = *(const float4*)(ep + i), e1 = *(const float4*)(ep + i + 4);
        float4 c0 = *(const float4*)(cr + i), c1 = *(const float4*)(cr + i + 4);
        s16x8 v;
        v[0] = f2bf(e0.x + c0.x); v[1] = f2bf(e0.y + c0.y);
        v[2] = f2bf(e0.z + c0.z); v[3] = f2bf(e0.w + c0.w);
        v[4] = f2bf(e1.x + c1.x); v[5] = f2bf(e1.y + c1.y);
        v[6] = f2bf(e1.z + c1.z); v[7] = f2bf(e1.w + c1.w);
        *(s16x8*)(ebf + i) = v;
    }
}

// ------------------------------------------------ LN kernels
__global__ __launch_bounds__(256) void k_ln_perc(
    const float* __restrict__ sig, const float* __restrict__ act,
    const float* __restrict__ pers, const float* __restrict__ chr,
    const float* __restrict__ lng, const float* __restrict__ lnb,
    short* __restrict__ percln)
{
    const int t = threadIdx.x, l = t & 63, w = t >> 6;
    const int row = blockIdx.x * 4 + w;
    const int n = row & (NAG - 1);
    const int c0 = l * 8;
    float v[8];
    if (l < 32) {
        const float* sp = sig  + (size_t)row * D + c0;
        const float* pp = pers + (size_t)n * D + c0;
        const float* cp = chr  + (size_t)n * D + c0;
        float4 s0 = *(const float4*)sp, s1 = *(const float4*)(sp + 4);
        float4 p0 = *(const float4*)pp, p1 = *(const float4*)(pp + 4);
        float4 q0 = *(const float4*)cp, q1 = *(const float4*)(cp + 4);
        v[0] = s0.x * (1.f + 0.1f * (p0.x + 0.3f * q0.x));
        v[1] = s0.y * (1.f + 0.1f * (p0.y + 0.3f * q0.y));
        v[2] = s0.z * (1.f + 0.1f * (p0.z + 0.3f * q0.z));
        v[3] = s0.w * (1.f + 0.1f * (p0.w + 0.3f * q0.w));
        v[4] = s1.x * (1.f + 0.1f * (p1.x + 0.3f * q1.x));
        v[5] = s1.y * (1.f + 0.1f * (p1.y + 0.3f * q1.y));
        v[6] = s1.z * (1.f + 0.1f * (p1.z + 0.3f * q1.z));
        v[7] = s1.w * (1.f + 0.1f * (p1.w + 0.3f * q1.w));
    } else {
        const float* ap = act + (size_t)row * D + (c0 - D);
        float4 a0 = *(const float4*)ap, a1 = *(const float4*)(ap + 4);
        v[0] = a0.x; v[1] = a0.y; v[2] = a0.z; v[3] = a0.w;
        v[4] = a1.x; v[5] = a1.y; v[6] = a1.z; v[7] = a1.w;
    }
    float s = 0.f;
    #pragma unroll
    for (int i = 0; i < 8; ++i) s += v[i];
    #pragma unroll
    for (int m = 1; m < 64; m <<= 1) s += __shfl_xor(s, m);
    const float mu = s * (1.0f / 512.0f);
    float q = 0.f;
    #pragma unroll
    for (int i = 0; i < 8; ++i) { float c = v[i] - mu; q += c * c; }
    #pragma unroll
    for (int m = 1; m < 64; m <<= 1) q += __shfl_xor(q, m);
    const float rstd = rsqrtf(q * (1.0f / 512.0f) + 1e-5f);
    float4 g0 = *(const float4*)(lng + c0), g1 = *(const float4*)(lng + c0 + 4);
    float4 b0 = *(const float4*)(lnb + c0), b1 = *(const float4*)(lnb + c0 + 4);
    const float gg[8] = {g0.x, g0.y, g0.z, g0.w, g1.x, g1.y, g1.z, g1.w};
    const float bb[8] = {b0.x, b0.y, b0.z, b0.w, b1.x, b1.y, b1.z, b1.w};
    s16x8 o;
    #pragma unroll
    for (int i = 0; i < 8; ++i) o[i] = f2bf((v[i] - mu) * rstd * gg[i] + bb[i]);
    *(s16x8*)(percln + (size_t)row * D2 + c0) = o;
}

__global__ __launch_bounds__(256) void k_ln_dec(
    const short* __restrict__ percbf, const float* __restrict__ rpart,
    const float* __restrict__ bfrom, const float* __restrict__ sim_part,
    const float* __restrict__ lng, const float* __restrict__ lnb,
    short* __restrict__ decln)
{
    const int t = threadIdx.x, l = t & 63, w = t >> 6;
    const int row = blockIdx.x * 4 + w;
    const int c0 = l * 8;
    float sr = (l < QSPL) ? sim_part[l * NROWS + row] : 0.f;
    #pragma unroll
    for (int m = 1; m < 32; m <<= 1) sr += __shfl_xor(sr, m);
    sr = __shfl(sr, 0);
    const float strength = sigmoid_f(sr * (1.0f / (float)HH));

    float v[8];
    if (l < 32) {
        s16x8 pv = *(const s16x8*)(percbf + (size_t)row * D + c0);
        #pragma unroll
        for (int i = 0; i < 8; ++i) v[i] = bf2f(pv[i]);
    } else {
        const int c = c0 - D;
        float a[8] = {0, 0, 0, 0, 0, 0, 0, 0};
        for (int ks = 0; ks < KSPL; ++ks) {
            const float* rp = rpart + ((size_t)ks * NROWS + row) * D + c;
            float4 x0 = *(const float4*)rp, x1 = *(const float4*)(rp + 4);
            a[0] += x0.x; a[1] += x0.y; a[2] += x0.z; a[3] += x0.w;
            a[4] += x1.x; a[5] += x1.y; a[6] += x1.z; a[7] += x1.w;
        }
        float4 f0 = *(const float4*)(bfrom + c), f1 = *(const float4*)(bfrom + c + 4);
        const float fb[8] = {f0.x, f0.y, f0.z, f0.w, f1.x, f1.y, f1.z, f1.w};
        #pragma unroll
        for (int i = 0; i < 8; ++i) v[i] = (a[i] + fb[i]) * strength;
    }
    float s = 0.f;
    #pragma unroll
    for (int i = 0; i < 8; ++i) s += v[i];
    #pragma unroll
    for (int m = 1; m < 64; m <<= 1) s += __shfl_xor(s, m);
    const float mu = s * (1.0f / 512.0f);
    float q = 0.f;
    #pragma unroll
    for (int i = 0; i < 8; ++i) { float c = v[i] - mu; q += c * c; }
    #pragma unroll
    for (int m = 1; m < 64; m <<= 1) q += __shfl_xor(q, m);
    const float rstd = rsqrtf(q * (1.0f / 512.0f) + 1e-5f);
    float4 g0 = *(const float4*)(lng + c0), g1 = *(const float4*)(lng + c0 + 4);
    float4 b0 = *(const float4*)(lnb + c0), b1 = *(const float4*)(lnb + c0 + 4);
    const float gg[8] = {g0.x, g0.y, g0.z, g0.w, g1.x, g1.y, g1.z, g1.w};
    const float bb[8] = {b0.x, b0.y, b0.z, b0.w, b1.x, b1.y, b1.z, b1.w};
    s16x8 o;
    #pragma unroll
    for (int i = 0; i < 8; ++i) o[i] = f2bf((v[i] - mu) * rstd * gg[i] + bb[i]);
    *(s16x8*)(decln + (size_t)row * D2 + c0) = o;
}

// ------------------------------------------------ small MFMA GEMM (16 rows x 256 cols)
template<int K, int EPI>
__global__ __launch_bounds__(256) void k_gemm16(
    const short* __restrict__ A, const short* __restrict__ BT,
    const float* __restrict__ bias, const float* __restrict__ pers,
    short* __restrict__ outbf, float* __restrict__ outf)
{
    __shared__ __align__(16) short as_[16 * K];
    const int t = threadIdx.x, l = t & 63, w = t >> 6;
    const int l15 = l & 15, lg = l >> 4;
    const int r0 = blockIdx.x * 16;

    #pragma unroll
    for (int p = 0; p < K / 128; ++p) {
        int e = p * 2048 + t * 8;
        int r = e / K, k = e % K;
        s16x8 v = *(const s16x8*)(A + (size_t)(r0 + r) * K + k);
        *(s16x8*)((char*)as_ + r * (2 * K) + ((k * 2) ^ ((r & 7) << 4))) = v;
    }
    __syncthreads();

    s16x8 afr[K / 32];
    const int axor = (l15 & 7) << 4;
    #pragma unroll
    for (int ks = 0; ks < K / 32; ++ks)
        afr[ks] = *(const s16x8*)((const char*)as_ + l15 * (2 * K)
                                  + (((ks * 32 + lg * 8) * 2) ^ axor));

    #pragma unroll
    for (int nt = 0; nt < 4; ++nt) {
        const int col = w * 64 + nt * 16 + l15;
        f32x4 acc = {0.f, 0.f, 0.f, 0.f};
        const short* bp_ = BT + (size_t)col * K + lg * 8;
        #pragma unroll
        for (int ks = 0; ks < K / 32; ++ks)
            acc = MFMA(afr[ks], *(const s16x8*)(bp_ + ks * 32), acc);
        const float bv = bias[col];
        #pragma unroll
        for (int j = 0; j < 4; ++j) {
            const int row = r0 + lg * 4 + j;
            float v = acc[j] + bv;
            if (EPI == 0) {
                outbf[(size_t)row * D + col] = f2bf(gelu_f(v));
            } else if (EPI == 1) {
                v *= (1.0f + 0.1f * pers[(size_t)(row & (NAG - 1)) * D + col]);
                outbf[(size_t)row * D + col] = f2bf(v);
            } else {
                outf[(size_t)row * D + col] = v;
            }
        }
    }
}

// ------------------------------------------------ gate GEMM + blend + LN(256) + mem_gate
__global__ __launch_bounds__(256) void k_gate(
    const float* __restrict__ prev, const short* __restrict__ decbf,
    const short* __restrict__ WgT, const float* __restrict__ bg,
    const float* __restrict__ lnog, const float* __restrict__ lnob,
    const float* __restrict__ Wm, const float* __restrict__ bm,
    const float* __restrict__ dot_part,
    float* __restrict__ out_st, short* __restrict__ stbf,
    float* __restrict__ out_mg)
{
    __shared__ __align__(16) short as_[16 * 512];
    __shared__ float red1[4][16], red2[4][16];
    const int t = threadIdx.x, l = t & 63, w = t >> 6;
    const int l15 = l & 15, lg = l >> 4;
    const int r0 = blockIdx.x * 16;

    #pragma unroll
    for (int p = 0; p < 2; ++p) {
        int e = p * 2048 + t * 8;
        int r = e >> 8, c = e & 255;
        const float* pp = prev + (size_t)(r0 + r) * D + c;
        float4 x0 = *(const float4*)pp, x1 = *(const float4*)(pp + 4);
        s16x8 v;
        v[0] = f2bf(x0.x); v[1] = f2bf(x0.y); v[2] = f2bf(x0.z); v[3] = f2bf(x0.w);
        v[4] = f2bf(x1.x); v[5] = f2bf(x1.y); v[6] = f2bf(x1.z); v[7] = f2bf(x1.w);
        *(s16x8*)((char*)as_ + r * 1024 + ((c * 2) ^ ((r & 7) << 4))) = v;
        s16x8 dv = *(const s16x8*)(decbf + (size_t)(r0 + r) * D + c);
        *(s16x8*)((char*)as_ + r * 1024 + (((256 + c) * 2) ^ ((r & 7) << 4))) = dv;
    }
    __syncthreads();

    s16x8 afr[16];
    const int axor = (l15 & 7) << 4;
    #pragma unroll
    for (int ks = 0; ks < 16; ++ks)
        afr[ks] = *(const s16x8*)((const char*)as_ + l15 * 1024
                                  + (((ks * 32 + lg * 8) * 2) ^ axor));

    float sv[4][4];
    #pragma unroll
    for (int nt = 0; nt < 4; ++nt) {
        const int col = w * 64 + nt * 16 + l15;
        f32x4 acc = {0.f, 0.f, 0.f, 0.f};
        const short* bp_ = WgT + (size_t)col * 512 + lg * 8;
        #pragma unroll
        for (int ks = 0; ks < 16; ++ks)
            acc = MFMA(afr[ks], *(const s16x8*)(bp_ + ks * 32), acc);
        const float bgv = bg[col];
        #pragma unroll
        for (int j = 0; j < 4; ++j) {
            const int rl = lg * 4 + j;
            const float pv = bf2f(*(const short*)((const char*)as_ + rl * 1024
                                    + ((col * 2) ^ ((rl & 7) << 4))));
            const float dv = bf2f(*(const short*)((const char*)as_ + rl * 1024
                                    + (((256 + col) * 2) ^ ((rl & 7) << 4))));
            const float g = sigmoid_f(acc[j] + bgv);
            sv[nt][j] = g * dv + (1.0f - g) * pv;
        }
    }

    float rs[4], rq[4];
    #pragma unroll
    for (int j = 0; j < 4; ++j) {
        float a = sv[0][j] + sv[1][j] + sv[2][j] + sv[3][j];
        float q = sv[0][j] * sv[0][j] + sv[1][j] * sv[1][j]
                + sv[2][j] * sv[2][j] + sv[3][j] * sv[3][j];
        #pragma unroll
        for (int m = 1; m < 16; m <<= 1) { a += __shfl_xor(a, m); q += __shfl_xor(q, m); }
        rs[j] = a; rq[j] = q;
    }
    if (l15 == 0) {
        #pragma unroll
        for (int j = 0; j < 4; ++j) { red1[w][lg * 4 + j] = rs[j]; red2[w][lg * 4 + j] = rq[j]; }
    }
    __syncthreads();

    float md[4];
    #pragma unroll
    for (int j = 0; j < 4; ++j) {
        const int lr = lg * 4 + j;
        const float tot  = red1[0][lr] + red1[1][lr] + red1[2][lr] + red1[3][lr];
        const float tot2 = red2[0][lr] + red2[1][lr] + red2[2][lr] + red2[3][lr];
        const float mu = tot * (1.0f / 256.0f);
        const float var = tot2 * (1.0f / 256.0f) - mu * mu;
        const float rstd = rsqrtf(var + 1e-5f);
        float m_ = 0.f;
        #pragma unroll
        for (int nt = 0; nt < 4; ++nt) {
            const int col = w * 64 + nt * 16 + l15;
            const float ns = (sv[nt][j] - mu) * rstd * lnog[col] + lnob[col];
            out_st[(size_t)(r0 + lr) * D + col] = ns;
            stbf[(size_t)(r0 + lr) * D + col] = f2bf(ns);
            m_ += ns * Wm[col];
        }
        #pragma unroll
        for (int m = 1; m < 16; m <<= 1) m_ += __shfl_xor(m_, m);
        md[j] = m_;
    }
    __syncthreads();
    if (l15 == 0) {
        #pragma unroll
        for (int j = 0; j < 4; ++j) red1[w][lg * 4 + j] = md[j];
    }
    __syncthreads();
    if (w == 0 && l15 == 0) {
        #pragma unroll
        for (int j = 0; j < 4; ++j) {
            const int lr = lg * 4 + j;
            const float tot = red1[0][lr] + red1[1][lr] + red1[2][lr] + red1[3][lr];
            float dotv = 0.f;
            for (int i = 0; i < QSPL; ++i) dotv += dot_part[i * NROWS + r0 + lr];
            out_mg[r0 + lr] = sigmoid_f(tot + dotv + bm[0]);
        }
    }
}

// ------------------------------------------------ K2: query GEMM, barrier-free loop
// 64 rows x 256 h per block; B direct from global; sim/dot partials.
__global__ __launch_bounds__(256) void k_query(
    const short* __restrict__ percbf, const short* __restrict__ WhT,
    const float* __restrict__ bh, const short* __restrict__ ebf,
    const float* __restrict__ keyf, const float* __restrict__ Wm,
    float* __restrict__ sim_part, float* __restrict__ dot_part)
{
    __shared__ __align__(16) short percs[64 * 256];   // 32 KB
    const int t = threadIdx.x;
    const int l = t & 63, w = t >> 6;
    const int l15 = l & 15, lg = l >> 4;
    const int r0 = blockIdx.y * 64;
    const int hb0 = blockIdx.x * (HH / QSPL);         // 256-wide h chunk
    const int axor = (l15 & 7) << 4;

    for (int p = 0; p < 8; ++p) {
        int e = p * 2048 + t * 8; int r = e >> 8, k = e & 255;
        s16x8 v = *(const s16x8*)(percbf + (r0 + r) * 256 + k);
        *(s16x8*)((char*)percs + r * 512 + ((k * 2) ^ ((r & 7) << 4))) = v;
    }
    __syncthreads();

    const int arow = (w * 16 + l15) * 512;
    s16x8 afr[8];
    #pragma unroll
    for (int ks = 0; ks < 8; ++ks)
        afr[ks] = *(const s16x8*)((const char*)percs + arow + ((ks * 64 + lg * 16) ^ axor));

    int rows[4], ns[4];
    #pragma unroll
    for (int j = 0; j < 4; ++j) {
        rows[j] = r0 + w * 16 + lg * 4 + j;
        ns[j] = rows[j] & (NAG - 1);
    }

    float psim[4] = {0, 0, 0, 0}, pdot[4] = {0, 0, 0, 0};

    #pragma unroll 2
    for (int nt = 0; nt < 16; ++nt) {
        const int h = hb0 + nt * 16 + l15;
        // early loads (hide under MFMA chain)
        float ev[4], kv[4];
        #pragma unroll
        for (int j = 0; j < 4; ++j) {
            ev[j] = bf2f(ebf[(size_t)rows[j] * HH + h]);
            kv[j] = keyf[(size_t)ns[j] * HH + h];
        }
        const float bhv = bh[h];
        const float wmv = Wm[D + h];
        const short* bp_ = WhT + (size_t)h * 256 + lg * 8;
        f32x4 acc = {0.f, 0.f, 0.f, 0.f};
        #pragma unroll
        for (int ks = 0; ks < 8; ++ks)
            acc = MFMA(afr[ks], *(const s16x8*)(bp_ + ks * 32), acc);
        #pragma unroll
        for (int j = 0; j < 4; ++j) {
            const float q = tanhf(acc[j] + bhv);
            psim[j] += q * ev[j] * kv[j];
            pdot[j] += q * wmv;
        }
    }

    #pragma unroll
    for (int j = 0; j < 4; ++j) {
        float s = psim[j], d = pdot[j];
        #pragma unroll
        for (int m = 1; m < 16; m <<= 1) { s += __shfl_xor(s, m); d += __shfl_xor(d, m); }
        if (l15 == 0) {
            sim_part[blockIdx.x * NROWS + rows[j]] = s;
            dot_part[blockIdx.x * NROWS + rows[j]] = d;
        }
    }
}

// ------------------------------------------------ K3: MFMA recall GEMM (K-split x8)
__global__ __launch_bounds__(256) void k_recall(
    const short* __restrict__ ebf, const short* __restrict__ WfT,
    float* __restrict__ rpart)
{
    __shared__ __align__(16) short as_[64 * 64];
    __shared__ __align__(16) short bs[256 * 64];
    const int t = threadIdx.x, l = t & 63, w = t >> 6;
    const int l15 = l & 15, lg = l >> 4;
    const int r0 = blockIdx.y * 64;
    const int kc0 = blockIdx.x * (HH / KSPL);
    const int axor = (l15 & 7) << 4;

    f32x4 acc[16];
    #pragma unroll
    for (int i = 0; i < 16; ++i) acc[i] = {0.f, 0.f, 0.f, 0.f};

    for (int kk = 0; kk < HH / KSPL; kk += 64) {
        __syncthreads();
        for (int p = 0; p < 2; ++p) {
            int e = p * 2048 + t * 8; int r = e >> 6, k = e & 63;
            s16x8 v = *(const s16x8*)(ebf + (size_t)(r0 + r) * HH + kc0 + kk + k);
            *(s16x8*)((char*)as_ + r * 128 + ((k * 2) ^ ((r & 7) << 4))) = v;
        }
        for (int p = 0; p < 8; ++p) {
            int e = p * 2048 + t * 8; int n = e >> 6, k = e & 63;
            s16x8 v = *(const s16x8*)(WfT + (size_t)n * HH + kc0 + kk + k);
            *(s16x8*)((char*)bs + n * 128 + ((k * 2) ^ ((n & 7) << 4))) = v;
        }
        __syncthreads();
        const int abase = (w * 16 + l15) * 128;
        s16x8 a0 = *(const s16x8*)((const char*)as_ + abase + ((lg * 16) ^ axor));
        s16x8 a1 = *(const s16x8*)((const char*)as_ + abase + ((64 + lg * 16) ^ axor));
        #pragma unroll
        for (int nt = 0; nt < 16; ++nt) {
            const int bbase = (nt * 16 + l15) * 128;
            s16x8 b0 = *(const s16x8*)((const char*)bs + bbase + ((lg * 16) ^ axor));
            s16x8 b1 = *(const s16x8*)((const char*)bs + bbase + ((64 + lg * 16) ^ axor));
            acc[nt] = MFMA(a0, b0, acc[nt]);
            acc[nt] = MFMA(a1, b1, acc[nt]);
        }
    }
    #pragma unroll
    for (int nt = 0; nt < 16; ++nt) {
        #pragma unroll
        for (int j = 0; j < 4; ++j) {
            const int row = r0 + w * 16 + lg * 4 + j;
            rpart[((size_t)blockIdx.x * NROWS + row) * D + nt * 16 + l15] = acc[nt][j];
        }
    }
}

// ------------------------------------------------ K5: exp GEMM + episodic write, barrier-free loop
__global__ __launch_bounds__(256) void k_exp(
    const short* __restrict__ stbf, const short* __restrict__ WhT,
    const float* __restrict__ bh, const float* __restrict__ ep,
    const float* __restrict__ keyf, const float* __restrict__ mg,
    float* __restrict__ out_exp, float* __restrict__ out_nep)
{
    __shared__ __align__(16) short sts[64 * 256];     // 32 KB
    const int t = threadIdx.x, l = t & 63, w = t >> 6;
    const int l15 = l & 15, lg = l >> 4;
    const int r0 = blockIdx.y * 64;
    const int hb0 = blockIdx.x * (HH / QSPL);
    const int axor = (l15 & 7) << 4;

    for (int p = 0; p < 8; ++p) {
        int e = p * 2048 + t * 8; int r = e >> 8, k = e & 255;
        s16x8 v = *(const s16x8*)(stbf + (r0 + r) * 256 + k);
        *(s16x8*)((char*)sts + r * 512 + ((k * 2) ^ ((r & 7) << 4))) = v;
    }
    int rows[4], ns[4];
    float mgv[4];
    #pragma unroll
    for (int j = 0; j < 4; ++j) {
        rows[j] = r0 + w * 16 + lg * 4 + j;
        ns[j] = rows[j] & (NAG - 1);
        mgv[j] = mg[rows[j]];
    }
    __syncthreads();

    const int arow = (w * 16 + l15) * 512;
    s16x8 afr[8];
    #pragma unroll
    for (int ks = 0; ks < 8; ++ks)
        afr[ks] = *(const s16x8*)((const char*)sts + arow + ((ks * 64 + lg * 16) ^ axor));

    #pragma unroll 2
    for (int nt = 0; nt < 16; ++nt) {
        const int h = hb0 + nt * 16 + l15;
        // early loads (hide under MFMA chain)
        float epv[4], kv[4];
        #pragma unroll
        for (int j = 0; j < 4; ++j) {
            epv[j] = ep[(size_t)rows[j] * HH + h];
            kv[j]  = keyf[(size_t)ns[j] * HH + h];
        }
        const float bhv = bh[h];
        const short* bp_ = WhT + (size_t)h * 256 + lg * 8;
        f32x4 acc = {0.f, 0.f, 0.f, 0.f};
        #pragma unroll
        for (int ks = 0; ks < 8; ++ks)
            acc = MFMA(afr[ks], *(const s16x8*)(bp_ + ks * 32), acc);
        #pragma unroll
        for (int j = 0; j < 4; ++j) {
            const float q = tanhf(acc[j] + bhv);
            const size_t idx = (size_t)rows[j] * HH + h;
            out_exp[idx] = q;
            out_nep[idx] = 0.95f * epv[j] + mgv[j] * q * kv[j];
        }
    }
}

// ----------------------------------------------------------------
extern "C" void kernel_launch(void* const* d_in, const int* in_sizes, int n_in,
                              void* d_out, int out_size, void* d_ws, size_t ws_size,
                              hipStream_t stream)
{
    const float* sig   = (const float*)d_in[0];
    const float* act   = (const float*)d_in[1];
    const float* ep    = (const float*)d_in[2];
    const float* cr    = (const float*)d_in[3];
    const float* prev  = (const float*)d_in[4];
    const float* lnpg  = (const float*)d_in[6];
    const float* lnpb  = (const float*)d_in[7];
    const float* Wp    = (const float*)d_in[8];
    const float* bp    = (const float*)d_in[9];
    const float* lndg  = (const float*)d_in[10];
    const float* lndb  = (const float*)d_in[11];
    const float* Wd1   = (const float*)d_in[12];
    const float* bd1   = (const float*)d_in[13];
    const float* Wd2   = (const float*)d_in[14];
    const float* bd2   = (const float*)d_in[15];
    const float* Wg    = (const float*)d_in[16];
    const float* bg    = (const float*)d_in[17];
    const float* Wa    = (const float*)d_in[18];
    const float* ba    = (const float*)d_in[19];
    const float* Wh    = (const float*)d_in[20];
    const float* bh    = (const float*)d_in[21];
    const float* Wf    = (const float*)d_in[22];
    const float* bfrom = (const float*)d_in[23];
    const float* Wm    = (const float*)d_in[24];
    const float* bm    = (const float*)d_in[25];
    const float* pers  = (const float*)d_in[26];
    const float* chr   = (const float*)d_in[27];
    const float* key   = (const float*)d_in[28];
    const float* lnog  = (const float*)d_in[29];
    const float* lnob  = (const float*)d_in[30];

    float* outp    = (float*)d_out;
    float* out_act = outp;                  // (B,N,D)
    float* out_st  = outp + 524288;         // (B,N,D)
    float* out_nep = outp + 1048576;        // (B,N,H)
    float* out_exp = outp + 17825792;       // (B,N,H)
    float* out_mg  = outp + 34603008;       // (B,N)

    // scratch in out_nep region (dead until k_exp, the last kernel, overwrites it)
    short* ebf      = (short*)out_nep;                       // 16.8M bf16 (32 MB)
    float* rpart    = out_nep + 8388608;                     // 8*2048*256 f32 (16 MB)
    short* WfT      = (short*)(out_nep + 8388608 + 4194304); // 2M bf16 (4 MB)
    float* sim_part = out_nep + 8388608 + 4194304 + 1048576; // 32*2048
    float* dot_part = sim_part + 65536;                      // 32*2048

    // scratch in out_exp region (also dead until k_exp)
    float* oe = out_exp;
    short* percln = (short*)oe;               // 2048x512 bf16
    short* decln  = (short*)(oe + 524288);    // 2048x512 bf16
    short* hbf    = (short*)(oe + 1048576);   // 2048x256 bf16
    short* decbf  = (short*)(oe + 1310720);   // 2048x256 bf16
    short* WpT    = (short*)(oe + 1572864);   // 256x512 bf16
    short* Wd1T   = (short*)(oe + 1638400);   // 256x512
    short* Wd2T   = (short*)(oe + 1703936);   // 256x256
    short* WgT    = (short*)(oe + 1736704);   // 256x512
    short* WaT    = (short*)(oe + 1802240);   // 256x256

    // k_exp inputs in d_ws (~6.3 MB)
    short* WhT    = (short*)d_ws;            // 8192x256 bf16
    short* percbf = WhT + 2097152;           // 2048x256 bf16
    short* stbf   = percbf + 524288;         // 2048x256 bf16

    k_transpose_bf<<<dim3(512), dim3(256), 0, stream>>>(Wh, WhT, 256, HH);
    k_transpose_bf<<<dim3(512), dim3(256), 0, stream>>>(Wf, WfT, HH, D);
    k_transpose_small<<<dim3(128), dim3(256), 0, stream>>>(
        Wp, Wd1, Wd2, Wg, Wa, WpT, Wd1T, Wd2T, WgT, WaT);
    k_prep_e<<<dim3(2048), dim3(256), 0, stream>>>(ep, cr, ebf);

    k_ln_perc<<<dim3(NROWS / 4), dim3(256), 0, stream>>>(
        sig, act, pers, chr, lnpg, lnpb, percln);
    k_gemm16<512, 0><<<dim3(NROWS / 16), dim3(256), 0, stream>>>(
        percln, WpT, bp, nullptr, percbf, nullptr);

    k_query<<<dim3(QSPL, NROWS / 64), dim3(256), 0, stream>>>(
        percbf, WhT, bh, ebf, key, Wm, sim_part, dot_part);
    k_recall<<<dim3(KSPL, NROWS / 64), dim3(256), 0, stream>>>(ebf, WfT, rpart);

    k_ln_dec<<<dim3(NROWS / 4), dim3(256), 0, stream>>>(
        percbf, rpart, bfrom, sim_part, lndg, lndb, decln);
    k_gemm16<512, 0><<<dim3(NROWS / 16), dim3(256), 0, stream>>>(
        decln, Wd1T, bd1, nullptr, hbf, nullptr);
    k_gemm16<256, 1><<<dim3(NROWS / 16), dim3(256), 0, stream>>>(
        hbf, Wd2T, bd2, pers, decbf, nullptr);
    k_gate<<<dim3(NROWS / 16), dim3(256), 0, stream>>>(
        prev, decbf, WgT, bg, lnog, lnob, Wm, bm, dot_part,
        out_st, stbf, out_mg);
    k_gemm16<256, 2><<<dim3(NROWS / 16), dim3(256), 0, stream>>>(
        stbf, WaT, ba, nullptr, nullptr, out_act);

    k_exp<<<dim3(QSPL, NROWS / 64), dim3(256), 0, stream>>>(
        stbf, WhT, bh, ep, key, out_mg, out_exp, out_nep);
}

// Round 5
// 300.717 us; speedup vs baseline: 1.0065x; 1.0065x over previous
//
#include <hip/hip_runtime.h>
#include <hip/hip_bf16.h>
#include <math.h>

#define D     256
#define D2    512
#define HH    8192
#define NAG   64
#define NROWS 2048
#define KSPL  16    // recall K-split
#define QSPL  32    // query/exp h-split

typedef short  s16x8 __attribute__((ext_vector_type(8)));
typedef __bf16 b16x8 __attribute__((ext_vector_type(8)));
typedef float  f32x4 __attribute__((ext_vector_type(4)));

template <typename T>
__device__ __forceinline__ auto mfma_try(T a, T b, f32x4 c, int)
    -> decltype(__builtin_amdgcn_mfma_f32_16x16x32_bf16(a, b, c, 0, 0, 0))
{ return __builtin_amdgcn_mfma_f32_16x16x32_bf16(a, b, c, 0, 0, 0); }

template <typename T>
__device__ __forceinline__ f32x4 mfma_try(T a, T b, f32x4 c, long)
{
    return __builtin_amdgcn_mfma_f32_16x16x32_bf16(
        __builtin_bit_cast(b16x8, a), __builtin_bit_cast(b16x8, b), c, 0, 0, 0);
}

__device__ __forceinline__ f32x4 MFMA(s16x8 a, s16x8 b, f32x4 c)
{ return mfma_try(a, b, c, 0); }

__device__ __forceinline__ float gelu_f(float x) {
    return 0.5f * x * (1.0f + erff(x * 0.70710678118654752440f));
}
__device__ __forceinline__ float sigmoid_f(float x) {
    return 1.0f / (1.0f + expf(-x));
}
__device__ __forceinline__ short f2bf(float x) {
    __hip_bfloat16 h(x);
    return __builtin_bit_cast(short, h);
}
__device__ __forceinline__ float bf2f(short s) {
    unsigned u = ((unsigned)(unsigned short)s) << 16;
    return __builtin_bit_cast(float, u);
}

// ------------------------------------------------ transpose f32 -> bf16
__device__ __forceinline__ void transpose_body(
    const float* __restrict__ src, short* __restrict__ dst, int R, int C, int lb)
{
    __shared__ float tl[64][65];
    const int t = threadIdx.x;
    const int Ctiles = C >> 6;
    const int bc = lb % Ctiles, br = lb / Ctiles;
    const int r0 = br * 64, c0 = bc * 64;
    for (int p = 0; p < 16; ++p) {
        int e = p * 256 + t; int i = e >> 6, j = e & 63;
        tl[i][j] = src[(size_t)(r0 + i) * C + c0 + j];
    }
    __syncthreads();
    for (int p = 0; p < 16; ++p) {
        int e = p * 256 + t; int jj = e >> 6, ii = e & 63;
        dst[(size_t)(c0 + jj) * R + r0 + ii] = f2bf(tl[ii][jj]);
    }
}

__global__ __launch_bounds__(256) void k_transpose_bf(
    const float* __restrict__ src, short* __restrict__ dst, int R, int C)
{
    transpose_body(src, dst, R, C, blockIdx.x);
}

__global__ __launch_bounds__(256) void k_transpose_small(
    const float* __restrict__ Wp,  const float* __restrict__ Wd1,
    const float* __restrict__ Wd2, const float* __restrict__ Wg,
    const float* __restrict__ Wa,
    short* __restrict__ WpT,  short* __restrict__ Wd1T,
    short* __restrict__ Wd2T, short* __restrict__ WgT,
    short* __restrict__ WaT)
{
    const int b = blockIdx.x;
    const float* src; short* dst; int R, C, b0;
    if      (b < 32)  { src = Wp;  dst = WpT;  R = 512; C = 256; b0 = 0;   }
    else if (b < 64)  { src = Wd1; dst = Wd1T; R = 512; C = 256; b0 = 32;  }
    else if (b < 80)  { src = Wd2; dst = Wd2T; R = 256; C = 256; b0 = 64;  }
    else if (b < 112) { src = Wg;  dst = WgT;  R = 512; C = 256; b0 = 80;  }
    else              { src = Wa;  dst = WaT;  R = 256; C = 256; b0 = 112; }
    transpose_body(src, dst, R, C, b - b0);
}

// ------------------------------------------------ LN kernels
__global__ __launch_bounds__(256) void k_ln_perc(
    const float* __restrict__ sig, const float* __restrict__ act,
    const float* __restrict__ pers, const float* __restrict__ chr,
    const float* __restrict__ lng, const float* __restrict__ lnb,
    short* __restrict__ percln)
{
    const int t = threadIdx.x, l = t & 63, w = t >> 6;
    const int row = blockIdx.x * 4 + w;
    const int n = row & (NAG - 1);
    const int c0 = l * 8;
    float v[8];
    if (l < 32) {
        const float* sp = sig  + (size_t)row * D + c0;
        const float* pp = pers + (size_t)n * D + c0;
        const float* cp = chr  + (size_t)n * D + c0;
        float4 s0 = *(const float4*)sp, s1 = *(const float4*)(sp + 4);
        float4 p0 = *(const float4*)pp, p1 = *(const float4*)(pp + 4);
        float4 q0 = *(const float4*)cp, q1 = *(const float4*)(cp + 4);
        v[0] = s0.x * (1.f + 0.1f * (p0.x + 0.3f * q0.x));
        v[1] = s0.y * (1.f + 0.1f * (p0.y + 0.3f * q0.y));
        v[2] = s0.z * (1.f + 0.1f * (p0.z + 0.3f * q0.z));
        v[3] = s0.w * (1.f + 0.1f * (p0.w + 0.3f * q0.w));
        v[4] = s1.x * (1.f + 0.1f * (p1.x + 0.3f * q1.x));
        v[5] = s1.y * (1.f + 0.1f * (p1.y + 0.3f * q1.y));
        v[6] = s1.z * (1.f + 0.1f * (p1.z + 0.3f * q1.z));
        v[7] = s1.w * (1.f + 0.1f * (p1.w + 0.3f * q1.w));
    } else {
        const float* ap = act + (size_t)row * D + (c0 - D);
        float4 a0 = *(const float4*)ap, a1 = *(const float4*)(ap + 4);
        v[0] = a0.x; v[1] = a0.y; v[2] = a0.z; v[3] = a0.w;
        v[4] = a1.x; v[5] = a1.y; v[6] = a1.z; v[7] = a1.w;
    }
    float s = 0.f;
    #pragma unroll
    for (int i = 0; i < 8; ++i) s += v[i];
    #pragma unroll
    for (int m = 1; m < 64; m <<= 1) s += __shfl_xor(s, m);
    const float mu = s * (1.0f / 512.0f);
    float q = 0.f;
    #pragma unroll
    for (int i = 0; i < 8; ++i) { float c = v[i] - mu; q += c * c; }
    #pragma unroll
    for (int m = 1; m < 64; m <<= 1) q += __shfl_xor(q, m);
    const float rstd = rsqrtf(q * (1.0f / 512.0f) + 1e-5f);
    float4 g0 = *(const float4*)(lng + c0), g1 = *(const float4*)(lng + c0 + 4);
    float4 b0 = *(const float4*)(lnb + c0), b1 = *(const float4*)(lnb + c0 + 4);
    const float gg[8] = {g0.x, g0.y, g0.z, g0.w, g1.x, g1.y, g1.z, g1.w};
    const float bb[8] = {b0.x, b0.y, b0.z, b0.w, b1.x, b1.y, b1.z, b1.w};
    s16x8 o;
    #pragma unroll
    for (int i = 0; i < 8; ++i) o[i] = f2bf((v[i] - mu) * rstd * gg[i] + bb[i]);
    *(s16x8*)(percln + (size_t)row * D2 + c0) = o;
}

__global__ __launch_bounds__(256) void k_ln_dec(
    const short* __restrict__ percbf, const float* __restrict__ rpart,
    const float* __restrict__ bfrom, const float* __restrict__ sim_part,
    const float* __restrict__ lng, const float* __restrict__ lnb,
    short* __restrict__ decln)
{
    const int t = threadIdx.x, l = t & 63, w = t >> 6;
    const int row = blockIdx.x * 4 + w;
    const int c0 = l * 8;
    float sr = (l < QSPL) ? sim_part[l * NROWS + row] : 0.f;
    #pragma unroll
    for (int m = 1; m < 32; m <<= 1) sr += __shfl_xor(sr, m);
    sr = __shfl(sr, 0);
    const float strength = sigmoid_f(sr * (1.0f / (float)HH));

    float v[8];
    if (l < 32) {
        s16x8 pv = *(const s16x8*)(percbf + (size_t)row * D + c0);
        #pragma unroll
        for (int i = 0; i < 8; ++i) v[i] = bf2f(pv[i]);
    } else {
        const int c = c0 - D;
        float a[8] = {0, 0, 0, 0, 0, 0, 0, 0};
        for (int ks = 0; ks < KSPL; ++ks) {
            const float* rp = rpart + ((size_t)ks * NROWS + row) * D + c;
            float4 x0 = *(const float4*)rp, x1 = *(const float4*)(rp + 4);
            a[0] += x0.x; a[1] += x0.y; a[2] += x0.z; a[3] += x0.w;
            a[4] += x1.x; a[5] += x1.y; a[6] += x1.z; a[7] += x1.w;
        }
        float4 f0 = *(const float4*)(bfrom + c), f1 = *(const float4*)(bfrom + c + 4);
        const float fb[8] = {f0.x, f0.y, f0.z, f0.w, f1.x, f1.y, f1.z, f1.w};
        #pragma unroll
        for (int i = 0; i < 8; ++i) v[i] = (a[i] + fb[i]) * strength;
    }
    float s = 0.f;
    #pragma unroll
    for (int i = 0; i < 8; ++i) s += v[i];
    #pragma unroll
    for (int m = 1; m < 64; m <<= 1) s += __shfl_xor(s, m);
    const float mu = s * (1.0f / 512.0f);
    float q = 0.f;
    #pragma unroll
    for (int i = 0; i < 8; ++i) { float c = v[i] - mu; q += c * c; }
    #pragma unroll
    for (int m = 1; m < 64; m <<= 1) q += __shfl_xor(q, m);
    const float rstd = rsqrtf(q * (1.0f / 512.0f) + 1e-5f);
    float4 g0 = *(const float4*)(lng + c0), g1 = *(const float4*)(lng + c0 + 4);
    float4 b0 = *(const float4*)(lnb + c0), b1 = *(const float4*)(lnb + c0 + 4);
    const float gg[8] = {g0.x, g0.y, g0.z, g0.w, g1.x, g1.y, g1.z, g1.w};
    const float bb[8] = {b0.x, b0.y, b0.z, b0.w, b1.x, b1.y, b1.z, b1.w};
    s16x8 o;
    #pragma unroll
    for (int i = 0; i < 8; ++i) o[i] = f2bf((v[i] - mu) * rstd * gg[i] + bb[i]);
    *(s16x8*)(decln + (size_t)row * D2 + c0) = o;
}

// ------------------------------------------------ small MFMA GEMM (16 rows x 256 cols)
template<int K, int EPI>
__global__ __launch_bounds__(256) void k_gemm16(
    const short* __restrict__ A, const short* __restrict__ BT,
    const float* __restrict__ bias, const float* __restrict__ pers,
    short* __restrict__ outbf, float* __restrict__ outf)
{
    __shared__ __align__(16) short as_[16 * K];
    const int t = threadIdx.x, l = t & 63, w = t >> 6;
    const int l15 = l & 15, lg = l >> 4;
    const int r0 = blockIdx.x * 16;

    #pragma unroll
    for (int p = 0; p < K / 128; ++p) {
        int e = p * 2048 + t * 8;
        int r = e / K, k = e % K;
        s16x8 v = *(const s16x8*)(A + (size_t)(r0 + r) * K + k);
        *(s16x8*)((char*)as_ + r * (2 * K) + ((k * 2) ^ ((r & 7) << 4))) = v;
    }
    __syncthreads();

    s16x8 afr[K / 32];
    const int axor = (l15 & 7) << 4;
    #pragma unroll
    for (int ks = 0; ks < K / 32; ++ks)
        afr[ks] = *(const s16x8*)((const char*)as_ + l15 * (2 * K)
                                  + (((ks * 32 + lg * 8) * 2) ^ axor));

    #pragma unroll
    for (int nt = 0; nt < 4; ++nt) {
        const int col = w * 64 + nt * 16 + l15;
        f32x4 acc = {0.f, 0.f, 0.f, 0.f};
        const short* bp_ = BT + (size_t)col * K + lg * 8;
        #pragma unroll
        for (int ks = 0; ks < K / 32; ++ks)
            acc = MFMA(afr[ks], *(const s16x8*)(bp_ + ks * 32), acc);
        const float bv = bias[col];
        #pragma unroll
        for (int j = 0; j < 4; ++j) {
            const int row = r0 + lg * 4 + j;
            float v = acc[j] + bv;
            if (EPI == 0) {
                outbf[(size_t)row * D + col] = f2bf(gelu_f(v));
            } else if (EPI == 1) {
                v *= (1.0f + 0.1f * pers[(size_t)(row & (NAG - 1)) * D + col]);
                outbf[(size_t)row * D + col] = f2bf(v);
            } else {
                outf[(size_t)row * D + col] = v;
            }
        }
    }
}

// ------------------------------------------------ gate GEMM + blend + LN(256) + mem_gate
__global__ __launch_bounds__(256) void k_gate(
    const float* __restrict__ prev, const short* __restrict__ decbf,
    const short* __restrict__ WgT, const float* __restrict__ bg,
    const float* __restrict__ lnog, const float* __restrict__ lnob,
    const float* __restrict__ Wm, const float* __restrict__ bm,
    const float* __restrict__ dot_part,
    float* __restrict__ out_st, short* __restrict__ stbf,
    float* __restrict__ out_mg)
{
    __shared__ __align__(16) short as_[16 * 512];
    __shared__ float red1[4][16], red2[4][16];
    const int t = threadIdx.x, l = t & 63, w = t >> 6;
    const int l15 = l & 15, lg = l >> 4;
    const int r0 = blockIdx.x * 16;

    #pragma unroll
    for (int p = 0; p < 2; ++p) {
        int e = p * 2048 + t * 8;
        int r = e >> 8, c = e & 255;
        const float* pp = prev + (size_t)(r0 + r) * D + c;
        float4 x0 = *(const float4*)pp, x1 = *(const float4*)(pp + 4);
        s16x8 v;
        v[0] = f2bf(x0.x); v[1] = f2bf(x0.y); v[2] = f2bf(x0.z); v[3] = f2bf(x0.w);
        v[4] = f2bf(x1.x); v[5] = f2bf(x1.y); v[6] = f2bf(x1.z); v[7] = f2bf(x1.w);
        *(s16x8*)((char*)as_ + r * 1024 + ((c * 2) ^ ((r & 7) << 4))) = v;
        s16x8 dv = *(const s16x8*)(decbf + (size_t)(r0 + r) * D + c);
        *(s16x8*)((char*)as_ + r * 1024 + (((256 + c) * 2) ^ ((r & 7) << 4))) = dv;
    }
    __syncthreads();

    s16x8 afr[16];
    const int axor = (l15 & 7) << 4;
    #pragma unroll
    for (int ks = 0; ks < 16; ++ks)
        afr[ks] = *(const s16x8*)((const char*)as_ + l15 * 1024
                                  + (((ks * 32 + lg * 8) * 2) ^ axor));

    float sv[4][4];
    #pragma unroll
    for (int nt = 0; nt < 4; ++nt) {
        const int col = w * 64 + nt * 16 + l15;
        f32x4 acc = {0.f, 0.f, 0.f, 0.f};
        const short* bp_ = WgT + (size_t)col * 512 + lg * 8;
        #pragma unroll
        for (int ks = 0; ks < 16; ++ks)
            acc = MFMA(afr[ks], *(const s16x8*)(bp_ + ks * 32), acc);
        const float bgv = bg[col];
        #pragma unroll
        for (int j = 0; j < 4; ++j) {
            const int rl = lg * 4 + j;
            const float pv = bf2f(*(const short*)((const char*)as_ + rl * 1024
                                    + ((col * 2) ^ ((rl & 7) << 4))));
            const float dv = bf2f(*(const short*)((const char*)as_ + rl * 1024
                                    + (((256 + col) * 2) ^ ((rl & 7) << 4))));
            const float g = sigmoid_f(acc[j] + bgv);
            sv[nt][j] = g * dv + (1.0f - g) * pv;
        }
    }

    float rs[4], rq[4];
    #pragma unroll
    for (int j = 0; j < 4; ++j) {
        float a = sv[0][j] + sv[1][j] + sv[2][j] + sv[3][j];
        float q = sv[0][j] * sv[0][j] + sv[1][j] * sv[1][j]
                + sv[2][j] * sv[2][j] + sv[3][j] * sv[3][j];
        #pragma unroll
        for (int m = 1; m < 16; m <<= 1) { a += __shfl_xor(a, m); q += __shfl_xor(q, m); }
        rs[j] = a; rq[j] = q;
    }
    if (l15 == 0) {
        #pragma unroll
        for (int j = 0; j < 4; ++j) { red1[w][lg * 4 + j] = rs[j]; red2[w][lg * 4 + j] = rq[j]; }
    }
    __syncthreads();

    float md[4];
    #pragma unroll
    for (int j = 0; j < 4; ++j) {
        const int lr = lg * 4 + j;
        const float tot  = red1[0][lr] + red1[1][lr] + red1[2][lr] + red1[3][lr];
        const float tot2 = red2[0][lr] + red2[1][lr] + red2[2][lr] + red2[3][lr];
        const float mu = tot * (1.0f / 256.0f);
        const float var = tot2 * (1.0f / 256.0f) - mu * mu;
        const float rstd = rsqrtf(var + 1e-5f);
        float m_ = 0.f;
        #pragma unroll
        for (int nt = 0; nt < 4; ++nt) {
            const int col = w * 64 + nt * 16 + l15;
            const float ns = (sv[nt][j] - mu) * rstd * lnog[col] + lnob[col];
            out_st[(size_t)(r0 + lr) * D + col] = ns;
            stbf[(size_t)(r0 + lr) * D + col] = f2bf(ns);
            m_ += ns * Wm[col];
        }
        #pragma unroll
        for (int m = 1; m < 16; m <<= 1) m_ += __shfl_xor(m_, m);
        md[j] = m_;
    }
    __syncthreads();
    if (l15 == 0) {
        #pragma unroll
        for (int j = 0; j < 4; ++j) red1[w][lg * 4 + j] = md[j];
    }
    __syncthreads();
    if (w == 0 && l15 == 0) {
        #pragma unroll
        for (int j = 0; j < 4; ++j) {
            const int lr = lg * 4 + j;
            const float tot = red1[0][lr] + red1[1][lr] + red1[2][lr] + red1[3][lr];
            float dotv = 0.f;
            for (int i = 0; i < QSPL; ++i) dotv += dot_part[i * NROWS + r0 + lr];
            out_mg[r0 + lr] = sigmoid_f(tot + dotv + bm[0]);
        }
    }
}

// ------------------------------------------------ fused prep + query:
// reads ep/cr f32 (float4), builds ebf tile in wave-private LDS, writes ebf,
// computes q = tanh(perc@Wh+bh), accumulates sim/dot partials.
__global__ __launch_bounds__(256) void k_prep_query(
    const float* __restrict__ ep, const float* __restrict__ cr,
    const short* __restrict__ percbf, const short* __restrict__ WhT,
    const float* __restrict__ bh, const float* __restrict__ keyf,
    const float* __restrict__ Wm,
    short* __restrict__ ebf, float* __restrict__ sim_part, float* __restrict__ dot_part)
{
    __shared__ __align__(16) short percs[64 * 256];   // 32 KB, swizzled
    __shared__ __align__(16) short ebft[64][72];      // 9 KB (wave-private rows)
    __shared__ __align__(16) short keyt[64][72];      // 9 KB
    const int t = threadIdx.x, l = t & 63, w = t >> 6;
    const int l15 = l & 15, lg = l >> 4;
    const int r0 = blockIdx.y * 64;
    const int hb0 = blockIdx.x * (HH / QSPL);         // 256-wide h chunk
    const int axor = (l15 & 7) << 4;

    for (int p = 0; p < 8; ++p) {
        int e = p * 2048 + t * 8; int r = e >> 8, k = e & 255;
        s16x8 v = *(const s16x8*)(percbf + (r0 + r) * 256 + k);
        *(s16x8*)((char*)percs + r * 512 + ((k * 2) ^ ((r & 7) << 4))) = v;
    }
    __syncthreads();

    const int arow = (w * 16 + l15) * 512;
    s16x8 afr[8];
    #pragma unroll
    for (int ks = 0; ks < 8; ++ks)
        afr[ks] = *(const s16x8*)((const char*)percs + arow + ((ks * 64 + lg * 16) ^ axor));

    const int lrow = w * 16 + (l >> 2);   // load-phase row within block
    const int lcol = (l & 3) * 16;        // load-phase col base within 64-h subchunk
    int rows[4];
    #pragma unroll
    for (int j = 0; j < 4; ++j) rows[j] = r0 + w * 16 + lg * 4 + j;

    float psim[4] = {0, 0, 0, 0}, pdot[4] = {0, 0, 0, 0};

    for (int sub = 0; sub < 4; ++sub) {
        const int h0 = hb0 + sub * 64;
        // ---- load ep/cr/key (float4, coalesced), build tiles (wave-private rows)
        const float* epp = ep   + (size_t)(r0 + lrow) * HH + h0 + lcol;
        const float* crp = cr   + (size_t)(r0 + lrow) * HH + h0 + lcol;
        const float* kpp = keyf + (size_t)lrow * HH + h0 + lcol;
        s16x8 v0, v1, kv0, kv1;
        #pragma unroll
        for (int q4 = 0; q4 < 2; ++q4) {
            float4 e0 = *(const float4*)(epp + q4 * 8),     e1 = *(const float4*)(epp + q4 * 8 + 4);
            float4 c0 = *(const float4*)(crp + q4 * 8),     c1 = *(const float4*)(crp + q4 * 8 + 4);
            float4 k0 = *(const float4*)(kpp + q4 * 8),     k1 = *(const float4*)(kpp + q4 * 8 + 4);
            s16x8& vv = q4 ? v1 : v0;
            s16x8& kk = q4 ? kv1 : kv0;
            vv[0] = f2bf(e0.x + c0.x); vv[1] = f2bf(e0.y + c0.y);
            vv[2] = f2bf(e0.z + c0.z); vv[3] = f2bf(e0.w + c0.w);
            vv[4] = f2bf(e1.x + c1.x); vv[5] = f2bf(e1.y + c1.y);
            vv[6] = f2bf(e1.z + c1.z); vv[7] = f2bf(e1.w + c1.w);
            kk[0] = f2bf(k0.x); kk[1] = f2bf(k0.y); kk[2] = f2bf(k0.z); kk[3] = f2bf(k0.w);
            kk[4] = f2bf(k1.x); kk[5] = f2bf(k1.y); kk[6] = f2bf(k1.z); kk[7] = f2bf(k1.w);
        }
        *(s16x8*)&ebft[lrow][lcol]     = v0;
        *(s16x8*)&ebft[lrow][lcol + 8] = v1;
        *(s16x8*)&keyt[lrow][lcol]     = kv0;
        *(s16x8*)&keyt[lrow][lcol + 8] = kv1;
        // ebf to global (for recall)
        short* egp = ebf + (size_t)(r0 + lrow) * HH + h0 + lcol;
        *(s16x8*)egp = v0;
        *(s16x8*)(egp + 8) = v1;
        // NOTE: no barrier — each wave writes & reads only rows [16w, 16w+16)

        // ---- query MFMA tiles + sim/dot epilogue
        #pragma unroll
        for (int tile = 0; tile < 4; ++tile) {
            const int h = h0 + tile * 16 + l15;
            const short* bp_ = WhT + (size_t)h * 256 + lg * 8;
            f32x4 acc = {0.f, 0.f, 0.f, 0.f};
            #pragma unroll
            for (int ks = 0; ks < 8; ++ks)
                acc = MFMA(afr[ks], *(const s16x8*)(bp_ + ks * 32), acc);
            const float bhv = bh[h];
            const float wmv = Wm[D + h];
            #pragma unroll
            for (int j = 0; j < 4; ++j) {
                const int rr = w * 16 + lg * 4 + j;
                const float q = tanhf(acc[j] + bhv);
                psim[j] += q * bf2f(ebft[rr][tile * 16 + l15]) * bf2f(keyt[rr][tile * 16 + l15]);
                pdot[j] += q * wmv;
            }
        }
    }

    #pragma unroll
    for (int j = 0; j < 4; ++j) {
        float s = psim[j], d = pdot[j];
        #pragma unroll
        for (int m = 1; m < 16; m <<= 1) { s += __shfl_xor(s, m); d += __shfl_xor(d, m); }
        if (l15 == 0) {
            sim_part[blockIdx.x * NROWS + rows[j]] = s;
            dot_part[blockIdx.x * NROWS + rows[j]] = d;
        }
    }
}

// ------------------------------------------------ K3: MFMA recall GEMM (K-split x16)
__global__ __launch_bounds__(256) void k_recall(
    const short* __restrict__ ebf, const short* __restrict__ WfT,
    float* __restrict__ rpart)
{
    __shared__ __align__(16) short as_[64 * 64];
    __shared__ __align__(16) short bs[256 * 64];
    const int t = threadIdx.x, l = t & 63, w = t >> 6;
    const int l15 = l & 15, lg = l >> 4;
    const int r0 = blockIdx.y * 64;
    const int kc0 = blockIdx.x * (HH / KSPL);
    const int axor = (l15 & 7) << 4;

    f32x4 acc[16];
    #pragma unroll
    for (int i = 0; i < 16; ++i) acc[i] = {0.f, 0.f, 0.f, 0.f};

    for (int kk = 0; kk < HH / KSPL; kk += 64) {
        __syncthreads();
        for (int p = 0; p < 2; ++p) {
            int e = p * 2048 + t * 8; int r = e >> 6, k = e & 63;
            s16x8 v = *(const s16x8*)(ebf + (size_t)(r0 + r) * HH + kc0 + kk + k);
            *(s16x8*)((char*)as_ + r * 128 + ((k * 2) ^ ((r & 7) << 4))) = v;
        }
        for (int p = 0; p < 8; ++p) {
            int e = p * 2048 + t * 8; int n = e >> 6, k = e & 63;
            s16x8 v = *(const s16x8*)(WfT + (size_t)n * HH + kc0 + kk + k);
            *(s16x8*)((char*)bs + n * 128 + ((k * 2) ^ ((n & 7) << 4))) = v;
        }
        __syncthreads();
        const int abase = (w * 16 + l15) * 128;
        s16x8 a0 = *(const s16x8*)((const char*)as_ + abase + ((lg * 16) ^ axor));
        s16x8 a1 = *(const s16x8*)((const char*)as_ + abase + ((64 + lg * 16) ^ axor));
        #pragma unroll
        for (int nt = 0; nt < 16; ++nt) {
            const int bbase = (nt * 16 + l15) * 128;
            s16x8 b0 = *(const s16x8*)((const char*)bs + bbase + ((lg * 16) ^ axor));
            s16x8 b1 = *(const s16x8*)((const char*)bs + bbase + ((64 + lg * 16) ^ axor));
            acc[nt] = MFMA(a0, b0, acc[nt]);
            acc[nt] = MFMA(a1, b1, acc[nt]);
        }
    }
    #pragma unroll
    for (int nt = 0; nt < 16; ++nt) {
        #pragma unroll
        for (int j = 0; j < 4; ++j) {
            const int row = r0 + w * 16 + lg * 4 + j;
            rpart[((size_t)blockIdx.x * NROWS + row) * D + nt * 16 + l15] = acc[nt][j];
        }
    }
}

// ------------------------------------------------ K5: exp GEMM + episodic write
// in-wave LDS transpose of the q tile -> fully vectorized (float4) global IO.
__global__ __launch_bounds__(256) void k_exp(
    const short* __restrict__ stbf, const short* __restrict__ WhT,
    const float* __restrict__ bh, const float* __restrict__ ep,
    const float* __restrict__ keyf, const float* __restrict__ mg,
    float* __restrict__ out_exp, float* __restrict__ out_nep)
{
    __shared__ __align__(16) short sts[64 * 256];     // 32 KB
    __shared__ __align__(16) float tls[4][16][68];    // 17 KB, wave-private transpose buf
    const int t = threadIdx.x, l = t & 63, w = t >> 6;
    const int l15 = l & 15, lg = l >> 4;
    const int r0 = blockIdx.y * 64;
    const int hb0 = blockIdx.x * (HH / QSPL);         // 256-wide h chunk
    const int axor = (l15 & 7) << 4;

    for (int p = 0; p < 8; ++p) {
        int e = p * 2048 + t * 8; int r = e >> 8, k = e & 255;
        s16x8 v = *(const s16x8*)(stbf + (r0 + r) * 256 + k);
        *(s16x8*)((char*)sts + r * 512 + ((k * 2) ^ ((r & 7) << 4))) = v;
    }
    const int lrow = l >> 2;              // IO-phase row within wave tile
    const int lcol = (l & 3) * 16;        // IO-phase col base within 64-h subchunk
    const int grow = r0 + w * 16 + lrow;  // global row for IO
    const float mgv = mg[grow];
    const int nag = grow & (NAG - 1);
    __syncthreads();

    const int arow = (w * 16 + l15) * 512;
    s16x8 afr[8];
    #pragma unroll
    for (int ks = 0; ks < 8; ++ks)
        afr[ks] = *(const s16x8*)((const char*)sts + arow + ((ks * 64 + lg * 16) ^ axor));

    for (int sub = 0; sub < 4; ++sub) {
        const int h0 = hb0 + sub * 64;
        // 4 independent MFMA chains (64 h)
        f32x4 acc[4];
        #pragma unroll
        for (int tile = 0; tile < 4; ++tile) {
            acc[tile] = {0.f, 0.f, 0.f, 0.f};
            const short* bp_ = WhT + (size_t)(h0 + tile * 16 + l15) * 256 + lg * 8;
            #pragma unroll
            for (int ks = 0; ks < 8; ++ks)
                acc[tile] = MFMA(afr[ks], *(const s16x8*)(bp_ + ks * 32), acc[tile]);
        }
        // tanh + transpose through wave-private LDS (no barrier: in-order per wave)
        #pragma unroll
        for (int tile = 0; tile < 4; ++tile) {
            const float bhv = bh[h0 + tile * 16 + l15];
            #pragma unroll
            for (int j = 0; j < 4; ++j)
                tls[w][lg * 4 + j][tile * 16 + l15] = tanhf(acc[tile][j] + bhv);
        }
        // vectorized IO: lane owns row (l>>2), 16 consecutive h
        const float* epp = ep   + (size_t)grow * HH + h0 + lcol;
        const float* kpp = keyf + (size_t)nag * HH + h0 + lcol;
        float* oe = out_exp + (size_t)grow * HH + h0 + lcol;
        float* on = out_nep + (size_t)grow * HH + h0 + lcol;
        #pragma unroll
        for (int q4 = 0; q4 < 4; ++q4) {
            f32x4 qv = *(const f32x4*)&tls[w][lrow][lcol + q4 * 4];
            float4 epv = *(const float4*)(epp + q4 * 4);
            float4 kv  = *(const float4*)(kpp + q4 * 4);
            *(f32x4*)(oe + q4 * 4) = qv;
            float4 nv;
            nv.x = 0.95f * epv.x + mgv * qv[0] * kv.x;
            nv.y = 0.95f * epv.y + mgv * qv[1] * kv.y;
            nv.z = 0.95f * epv.z + mgv * qv[2] * kv.z;
            nv.w = 0.95f * epv.w + mgv * qv[3] * kv.w;
            *(float4*)(on + q4 * 4) = nv;
        }
    }
}

// ----------------------------------------------------------------
extern "C" void kernel_launch(void* const* d_in, const int* in_sizes, int n_in,
                              void* d_out, int out_size, void* d_ws, size_t ws_size,
                              hipStream_t stream)
{
    const float* sig   = (const float*)d_in[0];
    const float* act   = (const float*)d_in[1];
    const float* ep    = (const float*)d_in[2];
    const float* cr    = (const float*)d_in[3];
    const float* prev  = (const float*)d_in[4];
    const float* lnpg  = (const float*)d_in[6];
    const float* lnpb  = (const float*)d_in[7];
    const float* Wp    = (const float*)d_in[8];
    const float* bp    = (const float*)d_in[9];
    const float* lndg  = (const float*)d_in[10];
    const float* lndb  = (const float*)d_in[11];
    const float* Wd1   = (const float*)d_in[12];
    const float* bd1   = (const float*)d_in[13];
    const float* Wd2   = (const float*)d_in[14];
    const float* bd2   = (const float*)d_in[15];
    const float* Wg    = (const float*)d_in[16];
    const float* bg    = (const float*)d_in[17];
    const float* Wa    = (const float*)d_in[18];
    const float* ba    = (const float*)d_in[19];
    const float* Wh    = (const float*)d_in[20];
    const float* bh    = (const float*)d_in[21];
    const float* Wf    = (const float*)d_in[22];
    const float* bfrom = (const float*)d_in[23];
    const float* Wm    = (const float*)d_in[24];
    const float* bm    = (const float*)d_in[25];
    const float* pers  = (const float*)d_in[26];
    const float* chr   = (const float*)d_in[27];
    const float* key   = (const float*)d_in[28];
    const float* lnog  = (const float*)d_in[29];
    const float* lnob  = (const float*)d_in[30];

    float* outp    = (float*)d_out;
    float* out_act = outp;                  // (B,N,D)
    float* out_st  = outp + 524288;         // (B,N,D)
    float* out_nep = outp + 1048576;        // (B,N,H)
    float* out_exp = outp + 17825792;       // (B,N,H)
    float* out_mg  = outp + 34603008;       // (B,N)

    // out_nep region (dead until k_exp): ebf [0,8.4M floats) + rpart [8.4M,16.8M)
    short* ebf   = (short*)out_nep;               // 16.8M bf16 (32 MB)
    float* rpart = out_nep + 8388608;             // 16*2048*256 f32 (32 MB)

    // out_exp region (dead until k_exp)
    float* oe = out_exp;
    short* percln   = (short*)oe;                 // 2048x512 bf16
    short* decln    = (short*)(oe + 524288);      // 2048x512 bf16
    short* hbf      = (short*)(oe + 1048576);     // 2048x256 bf16
    short* decbf    = (short*)(oe + 1310720);     // 2048x256 bf16
    short* WpT      = (short*)(oe + 1572864);     // 256x512
    short* Wd1T     = (short*)(oe + 1638400);     // 256x512
    short* Wd2T     = (short*)(oe + 1703936);     // 256x256
    short* WgT      = (short*)(oe + 1736704);     // 256x512
    short* WaT      = (short*)(oe + 1802240);     // 256x256 -> ends 1835008
    short* WfT      = (short*)(oe + 1835008);     // 256x8192 bf16 -> ends 2883584
    float* sim_part = oe + 2883584;               // 32*2048
    float* dot_part = sim_part + 65536;           // 32*2048 -> ends 3014656

    // k_exp inputs in d_ws (~6.3 MB)
    short* WhT    = (short*)d_ws;            // 8192x256 bf16
    short* percbf = WhT + 2097152;           // 2048x256 bf16
    short* stbf   = percbf + 524288;         // 2048x256 bf16

    k_transpose_bf<<<dim3(512), dim3(256), 0, stream>>>(Wh, WhT, 256, HH);
    k_transpose_bf<<<dim3(512), dim3(256), 0, stream>>>(Wf, WfT, HH, D);
    k_transpose_small<<<dim3(128), dim3(256), 0, stream>>>(
        Wp, Wd1, Wd2, Wg, Wa, WpT, Wd1T, Wd2T, WgT, WaT);

    k_ln_perc<<<dim3(NROWS / 4), dim3(256), 0, stream>>>(
        sig, act, pers, chr, lnpg, lnpb, percln);
    k_gemm16<512, 0><<<dim3(NROWS / 16), dim3(256), 0, stream>>>(
        percln, WpT, bp, nullptr, percbf, nullptr);

    k_prep_query<<<dim3(QSPL, NROWS / 64), dim3(256), 0, stream>>>(
        ep, cr, percbf, WhT, bh, key, Wm, ebf, sim_part, dot_part);

    k_recall<<<dim3(KSPL, NROWS / 64), dim3(256), 0, stream>>>(ebf, WfT, rpart);

    k_ln_dec<<<dim3(NROWS / 4), dim3(256), 0, stream>>>(
        percbf, rpart, bfrom, sim_part, lndg, lndb, decln);
    k_gemm16<512, 0><<<dim3(NROWS / 16), dim3(256), 0, stream>>>(
        decln, Wd1T, bd1, nullptr, hbf, nullptr);
    k_gemm16<256, 1><<<dim3(NROWS / 16), dim3(256), 0, stream>>>(
        hbf, Wd2T, bd2, pers, decbf, nullptr);
    k_gate<<<dim3(NROWS / 16), dim3(256), 0, stream>>>(
        prev, decbf, WgT, bg, lnog, lnob, Wm, bm, dot_part,
        out_st, stbf, out_mg);
    k_gemm16<256, 2><<<dim3(NROWS / 16), dim3(256), 0, stream>>>(
        stbf, WaT, ba, nullptr, nullptr, out_act);

    k_exp<<<dim3(QSPL, NROWS / 64), dim3(256), 0, stream>>>(
        stbf, WhT, bh, ep, key, out_mg, out_exp, out_nep);
}

// Round 6
// 294.826 us; speedup vs baseline: 1.0266x; 1.0200x over previous
//
#include <hip/hip_runtime.h>
#include <hip/hip_bf16.h>
#include <math.h>

#define D     256
#define D2    512
#define HH    8192
#define NAG   64
#define NROWS 2048
#define KSPL  16    // fused hdc h-split (rpart/sim/dot partials)
#define QSPL  32    // exp h-split

typedef short  s16x8 __attribute__((ext_vector_type(8)));
typedef __bf16 b16x8 __attribute__((ext_vector_type(8)));
typedef float  f32x4 __attribute__((ext_vector_type(4)));

template <typename T>
__device__ __forceinline__ auto mfma_try(T a, T b, f32x4 c, int)
    -> decltype(__builtin_amdgcn_mfma_f32_16x16x32_bf16(a, b, c, 0, 0, 0))
{ return __builtin_amdgcn_mfma_f32_16x16x32_bf16(a, b, c, 0, 0, 0); }

template <typename T>
__device__ __forceinline__ f32x4 mfma_try(T a, T b, f32x4 c, long)
{
    return __builtin_amdgcn_mfma_f32_16x16x32_bf16(
        __builtin_bit_cast(b16x8, a), __builtin_bit_cast(b16x8, b), c, 0, 0, 0);
}

__device__ __forceinline__ f32x4 MFMA(s16x8 a, s16x8 b, f32x4 c)
{ return mfma_try(a, b, c, 0); }

__device__ __forceinline__ float gelu_f(float x) {
    return 0.5f * x * (1.0f + erff(x * 0.70710678118654752440f));
}
__device__ __forceinline__ float sigmoid_f(float x) {
    return 1.0f / (1.0f + expf(-x));
}
__device__ __forceinline__ short f2bf(float x) {
    __hip_bfloat16 h(x);
    return __builtin_bit_cast(short, h);
}
__device__ __forceinline__ float bf2f(short s) {
    unsigned u = ((unsigned)(unsigned short)s) << 16;
    return __builtin_bit_cast(float, u);
}

// ------------------------------------------------ transpose f32 -> bf16
__device__ __forceinline__ void transpose_body(
    const float* __restrict__ src, short* __restrict__ dst, int R, int C, int lb)
{
    __shared__ float tl[64][65];
    const int t = threadIdx.x;
    const int Ctiles = C >> 6;
    const int bc = lb % Ctiles, br = lb / Ctiles;
    const int r0 = br * 64, c0 = bc * 64;
    for (int p = 0; p < 16; ++p) {
        int e = p * 256 + t; int i = e >> 6, j = e & 63;
        tl[i][j] = src[(size_t)(r0 + i) * C + c0 + j];
    }
    __syncthreads();
    for (int p = 0; p < 16; ++p) {
        int e = p * 256 + t; int jj = e >> 6, ii = e & 63;
        dst[(size_t)(c0 + jj) * R + r0 + ii] = f2bf(tl[ii][jj]);
    }
}

__global__ __launch_bounds__(256) void k_transpose_bf(
    const float* __restrict__ src, short* __restrict__ dst, int R, int C)
{
    transpose_body(src, dst, R, C, blockIdx.x);
}

__global__ __launch_bounds__(256) void k_transpose_small(
    const float* __restrict__ Wp,  const float* __restrict__ Wd1,
    const float* __restrict__ Wd2, const float* __restrict__ Wg,
    const float* __restrict__ Wa,
    short* __restrict__ WpT,  short* __restrict__ Wd1T,
    short* __restrict__ Wd2T, short* __restrict__ WgT,
    short* __restrict__ WaT)
{
    const int b = blockIdx.x;
    const float* src; short* dst; int R, C, b0;
    if      (b < 32)  { src = Wp;  dst = WpT;  R = 512; C = 256; b0 = 0;   }
    else if (b < 64)  { src = Wd1; dst = Wd1T; R = 512; C = 256; b0 = 32;  }
    else if (b < 80)  { src = Wd2; dst = Wd2T; R = 256; C = 256; b0 = 64;  }
    else if (b < 112) { src = Wg;  dst = WgT;  R = 512; C = 256; b0 = 80;  }
    else              { src = Wa;  dst = WaT;  R = 256; C = 256; b0 = 112; }
    transpose_body(src, dst, R, C, b - b0);
}

// ------------------------------------------------ key f32 -> bf16
__global__ __launch_bounds__(256) void k_keybf(
    const float* __restrict__ key, short* __restrict__ keybf)
{
    const size_t i = ((size_t)blockIdx.x * 256 + threadIdx.x) * 8;
    float4 a = *(const float4*)(key + i), b = *(const float4*)(key + i + 4);
    s16x8 v;
    v[0] = f2bf(a.x); v[1] = f2bf(a.y); v[2] = f2bf(a.z); v[3] = f2bf(a.w);
    v[4] = f2bf(b.x); v[5] = f2bf(b.y); v[6] = f2bf(b.z); v[7] = f2bf(b.w);
    *(s16x8*)(keybf + i) = v;
}

// ------------------------------------------------ LN kernels
__global__ __launch_bounds__(256) void k_ln_perc(
    const float* __restrict__ sig, const float* __restrict__ act,
    const float* __restrict__ pers, const float* __restrict__ chr,
    const float* __restrict__ lng, const float* __restrict__ lnb,
    short* __restrict__ percln)
{
    const int t = threadIdx.x, l = t & 63, w = t >> 6;
    const int row = blockIdx.x * 4 + w;
    const int n = row & (NAG - 1);
    const int c0 = l * 8;
    float v[8];
    if (l < 32) {
        const float* sp = sig  + (size_t)row * D + c0;
        const float* pp = pers + (size_t)n * D + c0;
        const float* cp = chr  + (size_t)n * D + c0;
        float4 s0 = *(const float4*)sp, s1 = *(const float4*)(sp + 4);
        float4 p0 = *(const float4*)pp, p1 = *(const float4*)(pp + 4);
        float4 q0 = *(const float4*)cp, q1 = *(const float4*)(cp + 4);
        v[0] = s0.x * (1.f + 0.1f * (p0.x + 0.3f * q0.x));
        v[1] = s0.y * (1.f + 0.1f * (p0.y + 0.3f * q0.y));
        v[2] = s0.z * (1.f + 0.1f * (p0.z + 0.3f * q0.z));
        v[3] = s0.w * (1.f + 0.1f * (p0.w + 0.3f * q0.w));
        v[4] = s1.x * (1.f + 0.1f * (p1.x + 0.3f * q1.x));
        v[5] = s1.y * (1.f + 0.1f * (p1.y + 0.3f * q1.y));
        v[6] = s1.z * (1.f + 0.1f * (p1.z + 0.3f * q1.z));
        v[7] = s1.w * (1.f + 0.1f * (p1.w + 0.3f * q1.w));
    } else {
        const float* ap = act + (size_t)row * D + (c0 - D);
        float4 a0 = *(const float4*)ap, a1 = *(const float4*)(ap + 4);
        v[0] = a0.x; v[1] = a0.y; v[2] = a0.z; v[3] = a0.w;
        v[4] = a1.x; v[5] = a1.y; v[6] = a1.z; v[7] = a1.w;
    }
    float s = 0.f;
    #pragma unroll
    for (int i = 0; i < 8; ++i) s += v[i];
    #pragma unroll
    for (int m = 1; m < 64; m <<= 1) s += __shfl_xor(s, m);
    const float mu = s * (1.0f / 512.0f);
    float q = 0.f;
    #pragma unroll
    for (int i = 0; i < 8; ++i) { float c = v[i] - mu; q += c * c; }
    #pragma unroll
    for (int m = 1; m < 64; m <<= 1) q += __shfl_xor(q, m);
    const float rstd = rsqrtf(q * (1.0f / 512.0f) + 1e-5f);
    float4 g0 = *(const float4*)(lng + c0), g1 = *(const float4*)(lng + c0 + 4);
    float4 b0 = *(const float4*)(lnb + c0), b1 = *(const float4*)(lnb + c0 + 4);
    const float gg[8] = {g0.x, g0.y, g0.z, g0.w, g1.x, g1.y, g1.z, g1.w};
    const float bb[8] = {b0.x, b0.y, b0.z, b0.w, b1.x, b1.y, b1.z, b1.w};
    s16x8 o;
    #pragma unroll
    for (int i = 0; i < 8; ++i) o[i] = f2bf((v[i] - mu) * rstd * gg[i] + bb[i]);
    *(s16x8*)(percln + (size_t)row * D2 + c0) = o;
}

__global__ __launch_bounds__(256) void k_ln_dec(
    const short* __restrict__ percbf, const float* __restrict__ rpart,
    const float* __restrict__ bfrom, const float* __restrict__ sim_part,
    const float* __restrict__ lng, const float* __restrict__ lnb,
    short* __restrict__ decln)
{
    const int t = threadIdx.x, l = t & 63, w = t >> 6;
    const int row = blockIdx.x * 4 + w;
    const int c0 = l * 8;
    float sr = (l < KSPL) ? sim_part[l * NROWS + row] : 0.f;
    #pragma unroll
    for (int m = 1; m < 16; m <<= 1) sr += __shfl_xor(sr, m);
    sr = __shfl(sr, 0);
    const float strength = sigmoid_f(sr * (1.0f / (float)HH));

    float v[8];
    if (l < 32) {
        s16x8 pv = *(const s16x8*)(percbf + (size_t)row * D + c0);
        #pragma unroll
        for (int i = 0; i < 8; ++i) v[i] = bf2f(pv[i]);
    } else {
        const int c = c0 - D;
        float a[8] = {0, 0, 0, 0, 0, 0, 0, 0};
        for (int ks = 0; ks < KSPL; ++ks) {
            const float* rp = rpart + ((size_t)ks * NROWS + row) * D + c;
            float4 x0 = *(const float4*)rp, x1 = *(const float4*)(rp + 4);
            a[0] += x0.x; a[1] += x0.y; a[2] += x0.z; a[3] += x0.w;
            a[4] += x1.x; a[5] += x1.y; a[6] += x1.z; a[7] += x1.w;
        }
        float4 f0 = *(const float4*)(bfrom + c), f1 = *(const float4*)(bfrom + c + 4);
        const float fb[8] = {f0.x, f0.y, f0.z, f0.w, f1.x, f1.y, f1.z, f1.w};
        #pragma unroll
        for (int i = 0; i < 8; ++i) v[i] = (a[i] + fb[i]) * strength;
    }
    float s = 0.f;
    #pragma unroll
    for (int i = 0; i < 8; ++i) s += v[i];
    #pragma unroll
    for (int m = 1; m < 64; m <<= 1) s += __shfl_xor(s, m);
    const float mu = s * (1.0f / 512.0f);
    float q = 0.f;
    #pragma unroll
    for (int i = 0; i < 8; ++i) { float c = v[i] - mu; q += c * c; }
    #pragma unroll
    for (int m = 1; m < 64; m <<= 1) q += __shfl_xor(q, m);
    const float rstd = rsqrtf(q * (1.0f / 512.0f) + 1e-5f);
    float4 g0 = *(const float4*)(lng + c0), g1 = *(const float4*)(lng + c0 + 4);
    float4 b0 = *(const float4*)(lnb + c0), b1 = *(const float4*)(lnb + c0 + 4);
    const float gg[8] = {g0.x, g0.y, g0.z, g0.w, g1.x, g1.y, g1.z, g1.w};
    const float bb[8] = {b0.x, b0.y, b0.z, b0.w, b1.x, b1.y, b1.z, b1.w};
    s16x8 o;
    #pragma unroll
    for (int i = 0; i < 8; ++i) o[i] = f2bf((v[i] - mu) * rstd * gg[i] + bb[i]);
    *(s16x8*)(decln + (size_t)row * D2 + c0) = o;
}

// ------------------------------------------------ small MFMA GEMM (16 rows x 256 cols)
template<int K, int EPI>
__global__ __launch_bounds__(256) void k_gemm16(
    const short* __restrict__ A, const short* __restrict__ BT,
    const float* __restrict__ bias, const float* __restrict__ pers,
    short* __restrict__ outbf, float* __restrict__ outf)
{
    __shared__ __align__(16) short as_[16 * K];
    const int t = threadIdx.x, l = t & 63, w = t >> 6;
    const int l15 = l & 15, lg = l >> 4;
    const int r0 = blockIdx.x * 16;

    #pragma unroll
    for (int p = 0; p < K / 128; ++p) {
        int e = p * 2048 + t * 8;
        int r = e / K, k = e % K;
        s16x8 v = *(const s16x8*)(A + (size_t)(r0 + r) * K + k);
        *(s16x8*)((char*)as_ + r * (2 * K) + ((k * 2) ^ ((r & 7) << 4))) = v;
    }
    __syncthreads();

    s16x8 afr[K / 32];
    const int axor = (l15 & 7) << 4;
    #pragma unroll
    for (int ks = 0; ks < K / 32; ++ks)
        afr[ks] = *(const s16x8*)((const char*)as_ + l15 * (2 * K)
                                  + (((ks * 32 + lg * 8) * 2) ^ axor));

    #pragma unroll
    for (int nt = 0; nt < 4; ++nt) {
        const int col = w * 64 + nt * 16 + l15;
        f32x4 acc = {0.f, 0.f, 0.f, 0.f};
        const short* bp_ = BT + (size_t)col * K + lg * 8;
        #pragma unroll
        for (int ks = 0; ks < K / 32; ++ks)
            acc = MFMA(afr[ks], *(const s16x8*)(bp_ + ks * 32), acc);
        const float bv = bias[col];
        #pragma unroll
        for (int j = 0; j < 4; ++j) {
            const int row = r0 + lg * 4 + j;
            float v = acc[j] + bv;
            if (EPI == 0) {
                outbf[(size_t)row * D + col] = f2bf(gelu_f(v));
            } else if (EPI == 1) {
                v *= (1.0f + 0.1f * pers[(size_t)(row & (NAG - 1)) * D + col]);
                outbf[(size_t)row * D + col] = f2bf(v);
            } else {
                outf[(size_t)row * D + col] = v;
            }
        }
    }
}

// ------------------------------------------------ gate GEMM + blend + LN(256) + mem_gate
__global__ __launch_bounds__(256) void k_gate(
    const float* __restrict__ prev, const short* __restrict__ decbf,
    const short* __restrict__ WgT, const float* __restrict__ bg,
    const float* __restrict__ lnog, const float* __restrict__ lnob,
    const float* __restrict__ Wm, const float* __restrict__ bm,
    const float* __restrict__ dot_part,
    float* __restrict__ out_st, short* __restrict__ stbf,
    float* __restrict__ out_mg)
{
    __shared__ __align__(16) short as_[16 * 512];
    __shared__ float red1[4][16], red2[4][16];
    const int t = threadIdx.x, l = t & 63, w = t >> 6;
    const int l15 = l & 15, lg = l >> 4;
    const int r0 = blockIdx.x * 16;

    #pragma unroll
    for (int p = 0; p < 2; ++p) {
        int e = p * 2048 + t * 8;
        int r = e >> 8, c = e & 255;
        const float* pp = prev + (size_t)(r0 + r) * D + c;
        float4 x0 = *(const float4*)pp, x1 = *(const float4*)(pp + 4);
        s16x8 v;
        v[0] = f2bf(x0.x); v[1] = f2bf(x0.y); v[2] = f2bf(x0.z); v[3] = f2bf(x0.w);
        v[4] = f2bf(x1.x); v[5] = f2bf(x1.y); v[6] = f2bf(x1.z); v[7] = f2bf(x1.w);
        *(s16x8*)((char*)as_ + r * 1024 + ((c * 2) ^ ((r & 7) << 4))) = v;
        s16x8 dv = *(const s16x8*)(decbf + (size_t)(r0 + r) * D + c);
        *(s16x8*)((char*)as_ + r * 1024 + (((256 + c) * 2) ^ ((r & 7) << 4))) = dv;
    }
    __syncthreads();

    s16x8 afr[16];
    const int axor = (l15 & 7) << 4;
    #pragma unroll
    for (int ks = 0; ks < 16; ++ks)
        afr[ks] = *(const s16x8*)((const char*)as_ + l15 * 1024
                                  + (((ks * 32 + lg * 8) * 2) ^ axor));

    float sv[4][4];
    #pragma unroll
    for (int nt = 0; nt < 4; ++nt) {
        const int col = w * 64 + nt * 16 + l15;
        f32x4 acc = {0.f, 0.f, 0.f, 0.f};
        const short* bp_ = WgT + (size_t)col * 512 + lg * 8;
        #pragma unroll
        for (int ks = 0; ks < 16; ++ks)
            acc = MFMA(afr[ks], *(const s16x8*)(bp_ + ks * 32), acc);
        const float bgv = bg[col];
        #pragma unroll
        for (int j = 0; j < 4; ++j) {
            const int rl = lg * 4 + j;
            const float pv = bf2f(*(const short*)((const char*)as_ + rl * 1024
                                    + ((col * 2) ^ ((rl & 7) << 4))));
            const float dv = bf2f(*(const short*)((const char*)as_ + rl * 1024
                                    + (((256 + col) * 2) ^ ((rl & 7) << 4))));
            const float g = sigmoid_f(acc[j] + bgv);
            sv[nt][j] = g * dv + (1.0f - g) * pv;
        }
    }

    float rs[4], rq[4];
    #pragma unroll
    for (int j = 0; j < 4; ++j) {
        float a = sv[0][j] + sv[1][j] + sv[2][j] + sv[3][j];
        float q = sv[0][j] * sv[0][j] + sv[1][j] * sv[1][j]
                + sv[2][j] * sv[2][j] + sv[3][j] * sv[3][j];
        #pragma unroll
        for (int m = 1; m < 16; m <<= 1) { a += __shfl_xor(a, m); q += __shfl_xor(q, m); }
        rs[j] = a; rq[j] = q;
    }
    if (l15 == 0) {
        #pragma unroll
        for (int j = 0; j < 4; ++j) { red1[w][lg * 4 + j] = rs[j]; red2[w][lg * 4 + j] = rq[j]; }
    }
    __syncthreads();

    float md[4];
    #pragma unroll
    for (int j = 0; j < 4; ++j) {
        const int lr = lg * 4 + j;
        const float tot  = red1[0][lr] + red1[1][lr] + red1[2][lr] + red1[3][lr];
        const float tot2 = red2[0][lr] + red2[1][lr] + red2[2][lr] + red2[3][lr];
        const float mu = tot * (1.0f / 256.0f);
        const float var = tot2 * (1.0f / 256.0f) - mu * mu;
        const float rstd = rsqrtf(var + 1e-5f);
        float m_ = 0.f;
        #pragma unroll
        for (int nt = 0; nt < 4; ++nt) {
            const int col = w * 64 + nt * 16 + l15;
            const float ns = (sv[nt][j] - mu) * rstd * lnog[col] + lnob[col];
            out_st[(size_t)(r0 + lr) * D + col] = ns;
            stbf[(size_t)(r0 + lr) * D + col] = f2bf(ns);
            m_ += ns * Wm[col];
        }
        #pragma unroll
        for (int m = 1; m < 16; m <<= 1) m_ += __shfl_xor(m_, m);
        md[j] = m_;
    }
    __syncthreads();
    if (l15 == 0) {
        #pragma unroll
        for (int j = 0; j < 4; ++j) red1[w][lg * 4 + j] = md[j];
    }
    __syncthreads();
    if (w == 0 && l15 == 0) {
        #pragma unroll
        for (int j = 0; j < 4; ++j) {
            const int lr = lg * 4 + j;
            const float tot = red1[0][lr] + red1[1][lr] + red1[2][lr] + red1[3][lr];
            float dotv = 0.f;
            for (int i = 0; i < KSPL; ++i) dotv += dot_part[i * NROWS + r0 + lr];
            out_mg[r0 + lr] = sigmoid_f(tot + dotv + bm[0]);
        }
    }
}

// ------------------------------------------------ fused HDC: prep + query(sim/dot) + recall
// block = 64 rows x 512-h range; per 64-h chunk: e-tile feeds BOTH sim and recall.
__global__ __launch_bounds__(256) void k_hdc(
    const float* __restrict__ ep, const float* __restrict__ cr,
    const short* __restrict__ percbf, const short* __restrict__ WhT,
    const float* __restrict__ bh, const short* __restrict__ keybf,
    const float* __restrict__ Wm, const short* __restrict__ WfT,
    float* __restrict__ rpart, float* __restrict__ sim_part,
    float* __restrict__ dot_part)
{
    // overlay: [0,32768) percs during A staging; then
    //   [0,8192)      e-tile   (swizzled [64][64] bf16, recall A)
    //   [8192,17408)  ek-tile  ([64][72] bf16, e*key for sim)
    //   [17408,50176) WfT tile (swizzled [256][64] bf16, recall B)
    __shared__ __align__(16) char smem[50176];
    short* sEK = (short*)(smem + 8192);
    const int t = threadIdx.x, l = t & 63, w = t >> 6;
    const int l15 = l & 15, lg = l >> 4;
    const int r0 = blockIdx.y * 64;
    const int kc0 = blockIdx.x * (HH / KSPL);
    const int axor = (l15 & 7) << 4;

    // stage perc rows (swizzled) and hoist A fragments
    for (int p = 0; p < 8; ++p) {
        int e = p * 2048 + t * 8; int r = e >> 8, k = e & 255;
        s16x8 v = *(const s16x8*)(percbf + (size_t)(r0 + r) * 256 + k);
        *(s16x8*)(smem + r * 512 + ((k * 2) ^ ((r & 7) << 4))) = v;
    }
    __syncthreads();
    s16x8 afr[8];
    {
        const int arow = (w * 16 + l15) * 512;
        #pragma unroll
        for (int ks = 0; ks < 8; ++ks)
            afr[ks] = *(const s16x8*)(smem + arow + ((ks * 64 + lg * 16) ^ axor));
    }

    float psim[4] = {0, 0, 0, 0}, pdot[4] = {0, 0, 0, 0};
    f32x4 racc[16];
    #pragma unroll
    for (int i = 0; i < 16; ++i) racc[i] = {0.f, 0.f, 0.f, 0.f};

    const int erow = t >> 2;           // load-phase row 0..63
    const int ecol = (t & 3) * 16;     // load-phase col base

    for (int ch = 0; ch < HH / KSPL; ch += 64) {
        const int h0 = kc0 + ch;
        __syncthreads();   // previous chunk's compute done
        // ---- e-tile + ek-tile (coalesced f32 loads, once per h)
        {
            const float* epp = ep + (size_t)(r0 + erow) * HH + h0 + ecol;
            const float* crp = cr + (size_t)(r0 + erow) * HH + h0 + ecol;
            const short* kpp = keybf + (size_t)erow * HH + h0 + ecol;
            s16x8 kv0 = *(const s16x8*)kpp;
            s16x8 kv1 = *(const s16x8*)(kpp + 8);
            s16x8 ev0, ev1, xv0, xv1;
            #pragma unroll
            for (int g = 0; g < 2; ++g) {
                float4 a0 = *(const float4*)(epp + g * 8), a1 = *(const float4*)(epp + g * 8 + 4);
                float4 b0 = *(const float4*)(crp + g * 8), b1 = *(const float4*)(crp + g * 8 + 4);
                float sums[8] = {a0.x + b0.x, a0.y + b0.y, a0.z + b0.z, a0.w + b0.w,
                                 a1.x + b1.x, a1.y + b1.y, a1.z + b1.z, a1.w + b1.w};
                s16x8& E = g ? ev1 : ev0;
                s16x8& X = g ? xv1 : xv0;
                s16x8& K = g ? kv1 : kv0;
                #pragma unroll
                for (int i = 0; i < 8; ++i) {
                    E[i] = f2bf(sums[i]);
                    X[i] = f2bf(sums[i] * bf2f(K[i]));
                }
            }
            *(s16x8*)(smem + erow * 128 + ((ecol * 2) ^ ((erow & 7) << 4))) = ev0;
            *(s16x8*)(smem + erow * 128 + (((ecol + 8) * 2) ^ ((erow & 7) << 4))) = ev1;
            *(s16x8*)(sEK + erow * 72 + ecol) = xv0;
            *(s16x8*)(sEK + erow * 72 + ecol + 8) = xv1;
        }
        // ---- WfT chunk -> swizzled B tile
        {
            const short* wfp = WfT + (size_t)t * HH + h0;
            #pragma unroll
            for (int g = 0; g < 8; ++g) {
                s16x8 v = *(const s16x8*)(wfp + g * 8);
                *(s16x8*)(smem + 17408 + t * 128 + ((g * 16) ^ ((t & 7) << 4))) = v;
            }
        }
        __syncthreads();
        // ---- query phase: q = tanh(perc@Wh+bh); sim/dot accumulate
        #pragma unroll
        for (int nt = 0; nt < 4; ++nt) {
            const int h = h0 + nt * 16 + l15;
            const short* bp_ = WhT + (size_t)h * 256 + lg * 8;
            f32x4 acc = {0.f, 0.f, 0.f, 0.f};
            #pragma unroll
            for (int ks = 0; ks < 8; ++ks)
                acc = MFMA(afr[ks], *(const s16x8*)(bp_ + ks * 32), acc);
            const float bhv = bh[h];
            const float wmv = Wm[D + h];
            #pragma unroll
            for (int j = 0; j < 4; ++j) {
                const int rr = w * 16 + lg * 4 + j;
                const float q = tanhf(acc[j] + bhv);
                psim[j] += q * bf2f(sEK[rr * 72 + nt * 16 + l15]);
                pdot[j] += q * wmv;
            }
        }
        // ---- recall phase: racc += e-tile @ WfT-tile (all LDS-fed)
        {
            const int abase = (w * 16 + l15) * 128;
            s16x8 a0 = *(const s16x8*)(smem + abase + ((lg * 16) ^ axor));
            s16x8 a1 = *(const s16x8*)(smem + abase + ((64 + lg * 16) ^ axor));
            #pragma unroll
            for (int nt = 0; nt < 16; ++nt) {
                const int bbase = 17408 + (nt * 16 + l15) * 128;
                s16x8 b0 = *(const s16x8*)(smem + bbase + ((lg * 16) ^ axor));
                s16x8 b1 = *(const s16x8*)(smem + bbase + ((64 + lg * 16) ^ axor));
                racc[nt] = MFMA(a0, b0, racc[nt]);
                racc[nt] = MFMA(a1, b1, racc[nt]);
            }
        }
    }

    // ---- epilogue: rpart + sim/dot partials
    #pragma unroll
    for (int nt = 0; nt < 16; ++nt) {
        #pragma unroll
        for (int j = 0; j < 4; ++j) {
            const int row = r0 + w * 16 + lg * 4 + j;
            rpart[((size_t)blockIdx.x * NROWS + row) * D + nt * 16 + l15] = racc[nt][j];
        }
    }
    #pragma unroll
    for (int j = 0; j < 4; ++j) {
        float s = psim[j], d2 = pdot[j];
        #pragma unroll
        for (int m = 1; m < 16; m <<= 1) { s += __shfl_xor(s, m); d2 += __shfl_xor(d2, m); }
        if (l15 == 0) {
            const int row = r0 + w * 16 + lg * 4 + j;
            sim_part[blockIdx.x * NROWS + row] = s;
            dot_part[blockIdx.x * NROWS + row] = d2;
        }
    }
}

// ------------------------------------------------ K5: exp GEMM + episodic write
// in-wave LDS transpose of the q tile -> fully vectorized (float4) global IO.
__global__ __launch_bounds__(256) void k_exp(
    const short* __restrict__ stbf, const short* __restrict__ WhT,
    const float* __restrict__ bh, const float* __restrict__ ep,
    const float* __restrict__ keyf, const float* __restrict__ mg,
    float* __restrict__ out_exp, float* __restrict__ out_nep)
{
    __shared__ __align__(16) short sts[64 * 256];     // 32 KB
    __shared__ __align__(16) float tls[4][16][68];    // 17 KB, wave-private transpose buf
    const int t = threadIdx.x, l = t & 63, w = t >> 6;
    const int l15 = l & 15, lg = l >> 4;
    const int r0 = blockIdx.y * 64;
    const int hb0 = blockIdx.x * (HH / QSPL);         // 256-wide h chunk
    const int axor = (l15 & 7) << 4;

    for (int p = 0; p < 8; ++p) {
        int e = p * 2048 + t * 8; int r = e >> 8, k = e & 255;
        s16x8 v = *(const s16x8*)(stbf + (r0 + r) * 256 + k);
        *(s16x8*)((char*)sts + r * 512 + ((k * 2) ^ ((r & 7) << 4))) = v;
    }
    const int lrow = l >> 2;              // IO-phase row within wave tile
    const int lcol = (l & 3) * 16;        // IO-phase col base within 64-h subchunk
    const int grow = r0 + w * 16 + lrow;  // global row for IO
    const float mgv = mg[grow];
    const int nag = grow & (NAG - 1);
    __syncthreads();

    const int arow = (w * 16 + l15) * 512;
    s16x8 afr[8];
    #pragma unroll
    for (int ks = 0; ks < 8; ++ks)
        afr[ks] = *(const s16x8*)((const char*)sts + arow + ((ks * 64 + lg * 16) ^ axor));

    for (int sub = 0; sub < 4; ++sub) {
        const int h0 = hb0 + sub * 64;
        f32x4 acc[4];
        #pragma unroll
        for (int tile = 0; tile < 4; ++tile) {
            acc[tile] = {0.f, 0.f, 0.f, 0.f};
            const short* bp_ = WhT + (size_t)(h0 + tile * 16 + l15) * 256 + lg * 8;
            #pragma unroll
            for (int ks = 0; ks < 8; ++ks)
                acc[tile] = MFMA(afr[ks], *(const s16x8*)(bp_ + ks * 32), acc[tile]);
        }
        #pragma unroll
        for (int tile = 0; tile < 4; ++tile) {
            const float bhv = bh[h0 + tile * 16 + l15];
            #pragma unroll
            for (int j = 0; j < 4; ++j)
                tls[w][lg * 4 + j][tile * 16 + l15] = tanhf(acc[tile][j] + bhv);
        }
        const float* epp = ep   + (size_t)grow * HH + h0 + lcol;
        const float* kpp = keyf + (size_t)nag * HH + h0 + lcol;
        float* oe = out_exp + (size_t)grow * HH + h0 + lcol;
        float* on = out_nep + (size_t)grow * HH + h0 + lcol;
        #pragma unroll
        for (int q4 = 0; q4 < 4; ++q4) {
            f32x4 qv = *(const f32x4*)&tls[w][lrow][lcol + q4 * 4];
            float4 epv = *(const float4*)(epp + q4 * 4);
            float4 kv  = *(const float4*)(kpp + q4 * 4);
            *(f32x4*)(oe + q4 * 4) = qv;
            float4 nv;
            nv.x = 0.95f * epv.x + mgv * qv[0] * kv.x;
            nv.y = 0.95f * epv.y + mgv * qv[1] * kv.y;
            nv.z = 0.95f * epv.z + mgv * qv[2] * kv.z;
            nv.w = 0.95f * epv.w + mgv * qv[3] * kv.w;
            *(float4*)(on + q4 * 4) = nv;
        }
    }
}

// ----------------------------------------------------------------
extern "C" void kernel_launch(void* const* d_in, const int* in_sizes, int n_in,
                              void* d_out, int out_size, void* d_ws, size_t ws_size,
                              hipStream_t stream)
{
    const float* sig   = (const float*)d_in[0];
    const float* act   = (const float*)d_in[1];
    const float* ep    = (const float*)d_in[2];
    const float* cr    = (const float*)d_in[3];
    const float* prev  = (const float*)d_in[4];
    const float* lnpg  = (const float*)d_in[6];
    const float* lnpb  = (const float*)d_in[7];
    const float* Wp    = (const float*)d_in[8];
    const float* bp    = (const float*)d_in[9];
    const float* lndg  = (const float*)d_in[10];
    const float* lndb  = (const float*)d_in[11];
    const float* Wd1   = (const float*)d_in[12];
    const float* bd1   = (const float*)d_in[13];
    const float* Wd2   = (const float*)d_in[14];
    const float* bd2   = (const float*)d_in[15];
    const float* Wg    = (const float*)d_in[16];
    const float* bg    = (const float*)d_in[17];
    const float* Wa    = (const float*)d_in[18];
    const float* ba    = (const float*)d_in[19];
    const float* Wh    = (const float*)d_in[20];
    const float* bh    = (const float*)d_in[21];
    const float* Wf    = (const float*)d_in[22];
    const float* bfrom = (const float*)d_in[23];
    const float* Wm    = (const float*)d_in[24];
    const float* bm    = (const float*)d_in[25];
    const float* pers  = (const float*)d_in[26];
    const float* chr   = (const float*)d_in[27];
    const float* key   = (const float*)d_in[28];
    const float* lnog  = (const float*)d_in[29];
    const float* lnob  = (const float*)d_in[30];

    float* outp    = (float*)d_out;
    float* out_act = outp;                  // (B,N,D)
    float* out_st  = outp + 524288;         // (B,N,D)
    float* out_nep = outp + 1048576;        // (B,N,H)
    float* out_exp = outp + 17825792;       // (B,N,H)
    float* out_mg  = outp + 34603008;       // (B,N)

    // out_nep region (dead until k_exp): keybf lower half, rpart upper half
    short* keybf = (short*)out_nep;               // 64x8192 bf16 (1 MB)
    float* rpart = out_nep + 8388608;             // 16*2048*256 f32 (32 MB)

    // out_exp region (dead until k_exp)
    float* oe = out_exp;
    short* percln   = (short*)oe;                 // 2048x512 bf16
    short* decln    = (short*)(oe + 524288);      // 2048x512 bf16
    short* hbf      = (short*)(oe + 1048576);     // 2048x256 bf16
    short* decbf    = (short*)(oe + 1310720);     // 2048x256 bf16
    short* WpT      = (short*)(oe + 1572864);     // 256x512
    short* Wd1T     = (short*)(oe + 1638400);     // 256x512
    short* Wd2T     = (short*)(oe + 1703936);     // 256x256
    short* WgT      = (short*)(oe + 1736704);     // 256x512
    short* WaT      = (short*)(oe + 1802240);     // 256x256 -> ends 1835008
    short* WfT      = (short*)(oe + 1835008);     // 256x8192 bf16 -> ends 2883584
    float* sim_part = oe + 2883584;               // 16*2048
    float* dot_part = oe + 2916352;               // 16*2048 -> ends 2949120

    // k_exp inputs in d_ws (~6.3 MB)
    short* WhT    = (short*)d_ws;            // 8192x256 bf16
    short* percbf = WhT + 2097152;           // 2048x256 bf16
    short* stbf   = percbf + 524288;         // 2048x256 bf16

    k_transpose_bf<<<dim3(512), dim3(256), 0, stream>>>(Wh, WhT, 256, HH);
    k_transpose_bf<<<dim3(512), dim3(256), 0, stream>>>(Wf, WfT, HH, D);
    k_transpose_small<<<dim3(128), dim3(256), 0, stream>>>(
        Wp, Wd1, Wd2, Wg, Wa, WpT, Wd1T, Wd2T, WgT, WaT);
    k_keybf<<<dim3(256), dim3(256), 0, stream>>>(key, keybf);

    k_ln_perc<<<dim3(NROWS / 4), dim3(256), 0, stream>>>(
        sig, act, pers, chr, lnpg, lnpb, percln);
    k_gemm16<512, 0><<<dim3(NROWS / 16), dim3(256), 0, stream>>>(
        percln, WpT, bp, nullptr, percbf, nullptr);

    k_hdc<<<dim3(KSPL, NROWS / 64), dim3(256), 0, stream>>>(
        ep, cr, percbf, WhT, bh, keybf, Wm, WfT, rpart, sim_part, dot_part);

    k_ln_dec<<<dim3(NROWS / 4), dim3(256), 0, stream>>>(
        percbf, rpart, bfrom, sim_part, lndg, lndb, decln);
    k_gemm16<512, 0><<<dim3(NROWS / 16), dim3(256), 0, stream>>>(
        decln, Wd1T, bd1, nullptr, hbf, nullptr);
    k_gemm16<256, 1><<<dim3(NROWS / 16), dim3(256), 0, stream>>>(
        hbf, Wd2T, bd2, pers, decbf, nullptr);
    k_gate<<<dim3(NROWS / 16), dim3(256), 0, stream>>>(
        prev, decbf, WgT, bg, lnog, lnob, Wm, bm, dot_part,
        out_st, stbf, out_mg);
    k_gemm16<256, 2><<<dim3(NROWS / 16), dim3(256), 0, stream>>>(
        stbf, WaT, ba, nullptr, nullptr, out_act);

    k_exp<<<dim3(QSPL, NROWS / 64), dim3(256), 0, stream>>>(
        stbf, WhT, bh, ep, key, out_mg, out_exp, out_nep);
}